// Round 1
// baseline (19846.103 us; speedup 1.0000x reference)
//
#include <hip/hip_runtime.h>
#include <hip/hip_cooperative_groups.h>

namespace cg = cooperative_groups;

// ---------------- model dims ----------------
// V=50000 E=128 H=160 D=196 A=224 BN=56, B=32, Tin=256, Ttgt=100
// encoder gates 4H=640, decoder gates 4D=784, 2H=320, D+2H=516, V-END=49998

// ---------------- ws layout (floats) ----------------
constexpr size_t oXf   = 0;                                // 8192 x 640
constexpr size_t oXb   = oXf   + (size_t)8192*640;
constexpr size_t oXd   = oXb   + (size_t)8192*640;         // 3200 x 784
constexpr size_t oEnc  = oXd   + (size_t)3200*784;         // 32 x 256 x 320
constexpr size_t oEncA = oEnc  + (size_t)32*256*320;       // 32 x 256 x 224
constexpr size_t oEs   = oEncA + (size_t)8192*224;         // 3200
constexpr size_t oHbE  = oEs   + 3200;                     // 2 dir x 2 buf x 32 x 160
constexpr size_t oCT   = oHbE  + 2*2*32*160;               // 2 x 32 x 160
constexpr size_t oHd   = oCT   + 2*32*160;                 // 2 x 32 x 196
constexpr size_t oC0   = oHd   + 2*32*196;                 // 32 x 196
constexpr size_t oU    = oC0   + 32*196;                   // 32 x 56
constexpr size_t oHWds = oU    + 32*56;                    // 2 x 32
constexpr size_t oCtxW = oHWds + 64;                       // 2 x 32
constexpr size_t oCopy = oCtxW + 64;                       // 2 x 32
constexpr size_t oZidx = oCopy + 64;                       // 2 x 32
constexpr size_t oPart = oZidx + 64;                       // 2 x 256
constexpr size_t oCl   = oPart + 512;                      // 32
constexpr size_t oFEnd = oCl   + 32;
// ints after floats: in_mapped[8192], cur_ids[3200]

// ---------------- device helpers ----------------
__device__ __forceinline__ float fast_tanh(float x){
  float e = __expf(-2.f*fabsf(x));
  float r = (1.f - e) * __builtin_amdgcn_rcpf(1.f + e);
  return copysignf(r, x);
}
__device__ __forceinline__ float sigm(float x){
  return __builtin_amdgcn_rcpf(1.f + __expf(-x));
}
__device__ __forceinline__ float block_sum(float v, float* red){
  #pragma unroll
  for (int o=32;o;o>>=1) v += __shfl_down(v,o);
  if ((threadIdx.x&63)==0) red[threadIdx.x>>6] = v;
  __syncthreads();
  v = red[0]+red[1]+red[2]+red[3];
  __syncthreads();
  return v;
}
__device__ __forceinline__ float block_max(float v, float* red){
  #pragma unroll
  for (int o=32;o;o>>=1) v = fmaxf(v,__shfl_down(v,o));
  if ((threadIdx.x&63)==0) red[threadIdx.x>>6] = v;
  __syncthreads();
  v = fmaxf(fmaxf(red[0],red[1]),fmaxf(red[2],red[3]));
  __syncthreads();
  return v;
}

// ---------------- prep: id mapping ----------------
__global__ void prep_kernel(const int* __restrict__ in_ids, const int* __restrict__ tgt,
                            int* __restrict__ in_mapped, int* __restrict__ cur_ids){
  int i = blockIdx.x*256 + threadIdx.x;
  if (i < 8192){
    int t = i >> 5, b = i & 31;
    int id = in_ids[b*256 + t];
    in_mapped[i] = (id >= 50000) ? 3 : id;
  }
  if (i < 3200){
    int k = i >> 5, b = i & 31;
    int id = (k == 0) ? 1 : tgt[b*100 + (k-1)];
    cur_ids[i] = (id >= 50000) ? 3 : id;
  }
}

// ---------------- generic row GEMM: out[r][g] = bias(g) + sum_k src(r,k)*W[g][k] ----------------
struct RGArgs{ const float* src; const int* gid; const float* emb; const float* W;
               const float* bias1; const float* bias2; float* out; int K; int N; };
__global__ void __launch_bounds__(256) rowgemm(RGArgs a){
  extern __shared__ float rl[];   // 8 x K
  const int tid = threadIdx.x;
  const int K = a.K, N = a.N;
  const size_t r0 = (size_t)blockIdx.x*8;
  for (int i = tid; i < 8*K; i += 256){
    int r = i / K, k = i - r*K;
    const float* srow = a.gid ? (a.emb + (size_t)a.gid[r0+r]*128)
                              : (a.src + (r0+r)*(size_t)K);
    rl[i] = srow[k];
  }
  __syncthreads();
  for (int g = tid; g < N; g += 256){
    const float* wr = a.W + (size_t)g*K;
    float acc[8];
    #pragma unroll
    for (int r=0;r<8;r++) acc[r]=0.f;
    for (int k=0;k<K;k+=4){
      float4 wv = *(const float4*)(wr+k);
      #pragma unroll
      for (int r=0;r<8;r++){
        float4 xv = *(const float4*)(rl + r*K + k);
        acc[r] += wv.x*xv.x + wv.y*xv.y + wv.z*xv.z + wv.w*xv.w;
      }
    }
    float bias = a.bias1[g] + (a.bias2 ? a.bias2[g] : 0.f);
    #pragma unroll
    for (int r=0;r<8;r++) a.out[(r0+r)*(size_t)N + g] = acc[r] + bias;
  }
}

// ---------------- es[r] = emb[gid[r]] . Wes ----------------
__global__ void es_kernel(const int* __restrict__ gid, const float* __restrict__ emb,
                          const float* __restrict__ Wes, float* __restrict__ es){
  int r = blockIdx.x, l = threadIdx.x;  // 64 threads = 1 wave
  const float* e = emb + (size_t)gid[r]*128;
  float acc = e[l]*Wes[l] + e[l+64]*Wes[l+64];
  #pragma unroll
  for (int o=32;o;o>>=1) acc += __shfl_down(acc,o);
  if (l==0) es[r] = acc;
}

// ---------------- encoder bidirectional LSTM scan (cooperative, grid=40) ----------------
struct EncArgs{ const float* Xf; const float* Xb; const float* Whf; const float* Whb;
                float* hbuf; float* enc; float* cT; };
__global__ void __launch_bounds__(256) enc_scan(EncArgs a){
  extern __shared__ float sm[];
  float* Wl = sm;           // [gate*8+jl][160]  = 5120
  float* hl = sm + 5120;    // [32][164]          = 5248
  const int wg = blockIdx.x;
  const int dir = wg/20, jwg = wg%20;
  const int tid = threadIdx.x;
  const int b = tid & 31, jl = tid >> 5;
  const int j = jwg*8 + jl;   // < 160 always
  const float* Wh = dir ? a.Whb : a.Whf;
  const float* X  = dir ? a.Xb  : a.Xf;
  float* hb = a.hbuf + dir*(2*32*160);
  for (int i = tid; i < 32*160; i += 256){
    int row = i/160, k = i - row*160;
    int gate = row >> 3, jj = row & 7;
    Wl[i] = Wh[((size_t)(gate*160 + jwg*8 + jj))*160 + k];
  }
  for (int i = tid; i < 32*160; i += 256) hb[i] = 0.f;
  float c = 0.f;
  const float4* w0 = (const float4*)(Wl + (0*8+jl)*160);
  const float4* w1 = (const float4*)(Wl + (1*8+jl)*160);
  const float4* w2 = (const float4*)(Wl + (2*8+jl)*160);
  const float4* w3 = (const float4*)(Wl + (3*8+jl)*160);
  cg::grid_group grid = cg::this_grid();
  grid.sync();
  for (int t = 0; t < 256; ++t){
    const int cur = t & 1;
    const int trow = dir ? (255 - t) : t;
    const float* xr = X + ((size_t)trow*32 + b)*640 + j;
    float g0 = xr[0], g1 = xr[160], g2 = xr[320], g3 = xr[480];
    __syncthreads();
    for (int i = tid; i < 32*160; i += 256){
      int bb = i/160, k = i - bb*160;
      hl[bb*164 + k] = hb[cur*5120 + i];
    }
    __syncthreads();
    const float4* hr = (const float4*)(hl + b*164);
    #pragma unroll 4
    for (int q = 0; q < 40; ++q){
      float4 hv = hr[q];
      float4 a0 = w0[q], a1 = w1[q], a2 = w2[q], a3 = w3[q];
      g0 += hv.x*a0.x + hv.y*a0.y + hv.z*a0.z + hv.w*a0.w;
      g1 += hv.x*a1.x + hv.y*a1.y + hv.z*a1.z + hv.w*a1.w;
      g2 += hv.x*a2.x + hv.y*a2.y + hv.z*a2.z + hv.w*a2.w;
      g3 += hv.x*a3.x + hv.y*a3.y + hv.z*a3.z + hv.w*a3.w;
    }
    float ig = sigm(g0), fg = sigm(g1), gc = fast_tanh(g2), og = sigm(g3);
    c = fg*c + ig*gc;
    float h = og * fast_tanh(c);
    hb[((t+1)&1)*5120 + b*160 + j] = h;
    a.enc[((size_t)b*256 + trow)*320 + dir*160 + j] = h;
    grid.sync();
  }
  a.cT[dir*5120 + b*160 + j] = c;
}

// ---------------- mid: h0/c0 projections ----------------
__global__ void mid_kernel(const float* __restrict__ enc, const float* __restrict__ cT,
                           const float* __restrict__ Weh, const float* __restrict__ beh,
                           const float* __restrict__ Wec, const float* __restrict__ bec,
                           float* __restrict__ h0, float* __restrict__ c0){
  __shared__ float hc[320], cc[320];
  int b = blockIdx.x, tid = threadIdx.x;
  if (tid < 160){
    hc[tid]     = enc[((size_t)b*256 + 255)*320 + tid];
    hc[160+tid] = enc[((size_t)b*256 + 0)*320 + 160 + tid];
    cc[tid]     = cT[b*160 + tid];
    cc[160+tid] = cT[5120 + b*160 + tid];
  }
  __syncthreads();
  for (int g = tid; g < 196; g += 256){
    const float* w1 = Weh + (size_t)g*320;
    const float* w2 = Wec + (size_t)g*320;
    float a1 = beh[g], a2 = bec[g];
    for (int k = 0; k < 320; ++k){ a1 += hc[k]*w1[k]; a2 += cc[k]*w2[k]; }
    h0[b*196 + g] = a1;
    c0[b*196 + g] = a2;
  }
}

// ---------------- decoder scan (cooperative, grid=256) ----------------
struct DecArgs{
  const float* Xd; const float* Whd; float* hd; const float* c0;
  const float* enc; const float* encA; const int* in_ids; const int* tgt;
  const float* es; const float* Wda; const float* Wca; const float* vat;
  const float* W1; const float* b1; const float* W2; const float* b2;
  const float* Wcs; const float* bcs; const float* Wds;
  float* u; float* hWds; float* ctxWcs; float* copyp; float* zidx; float* part;
  float* cl; float* out;
};

__device__ __forceinline__ void finalize_step(const DecArgs& A, int s, int tid, float& nll){
  if (tid < 32){
    int sl = s & 1, bb = tid;
    float se = 0.f;
    #pragma unroll
    for (int c2 = 0; c2 < 8; ++c2) se += A.part[sl*256 + bb*8 + c2];
    int nt2 = A.tgt[bb*100 + s];
    float xg = A.ctxWcs[sl*32+bb] + A.bcs[0] + A.hWds[sl*32+bb] + A.es[(size_t)s*32 + bb];
    float pg = 1.f/(1.f + __expf(-xg));
    float genp = (nt2 >= 2 && nt2 < 50000) ? (__expf(A.zidx[sl*32+bb]) / se) : 0.f;
    float p = pg*genp + (1.f - pg)*A.copyp[sl*32+bb];
    nll += -logf(p + 1e-9f);
  }
}

__global__ void __launch_bounds__(256) dec_scan(DecArgs A){
  extern __shared__ float sm[];
  float* Wl  = sm;          // 4*8*196 = 6272 (persistent, WGs 0..24)
  float* scr = sm + 6272;   // 6400 scratch (all phases)
  const int wg = blockIdx.x, tid = threadIdx.x;
  cg::grid_group grid = cg::this_grid();

  const int bp = tid & 31, jl = tid >> 5;
  const int j = wg*8 + jl;                 // valid only for wg<25
  float c = 0.f;                           // decoder LSTM cell (wg<25)
  if (wg < 25){
    for (int i = tid; i < 32*196; i += 256){
      int row = i/196, k = i - row*196;
      int gate = row >> 3, jj = row & 7;
      int jg = wg*8 + jj;
      Wl[i] = (jg < 196) ? A.Whd[((size_t)(gate*196 + jg))*196 + k] : 0.f;
    }
    if (j < 196) c = A.c0[bp*196 + j];
  }
  float cov = 0.f;    // coverage (wg<32, thread t=tid)
  float clr = 0.f;    // coverage-loss accumulator (wg<32, tid 0)
  float nll = 0.f;    // nll accumulator (wg==32, tid<32)

  const float4* w0 = (const float4*)(Wl + (0*8+jl)*196);
  const float4* w1 = (const float4*)(Wl + (1*8+jl)*196);
  const float4* w2 = (const float4*)(Wl + (2*8+jl)*196);
  const float4* w3 = (const float4*)(Wl + (3*8+jl)*196);

  for (int step = 0; step < 100; ++step){
    // ---- P1: decoder LSTM step (WGs 0..24) ----
    if (wg < 25){
      const int cur = step & 1;
      float g0=0.f,g1=0.f,g2=0.f,g3=0.f;
      if (j < 196){
        const float* xr = A.Xd + ((size_t)step*32 + bp)*784 + j;
        g0 = xr[0]; g1 = xr[196]; g2 = xr[392]; g3 = xr[588];
      }
      __syncthreads();
      for (int i = tid; i < 32*196; i += 256){
        int bb = i/196, k = i - bb*196;
        scr[bb*200 + k] = A.hd[cur*6272 + i];
      }
      __syncthreads();
      if (j < 196){
        const float4* hr = (const float4*)(scr + bp*200);
        #pragma unroll 7
        for (int q = 0; q < 49; ++q){
          float4 hv = hr[q];
          float4 a0 = w0[q], a1 = w1[q], a2 = w2[q], a3 = w3[q];
          g0 += hv.x*a0.x + hv.y*a0.y + hv.z*a0.z + hv.w*a0.w;
          g1 += hv.x*a1.x + hv.y*a1.y + hv.z*a1.z + hv.w*a1.w;
          g2 += hv.x*a2.x + hv.y*a2.y + hv.z*a2.z + hv.w*a2.w;
          g3 += hv.x*a3.x + hv.y*a3.y + hv.z*a3.z + hv.w*a3.w;
        }
        float ig = sigm(g0), fg = sigm(g1), gc = fast_tanh(g2), og = sigm(g3);
        c = fg*c + ig*gc;
        float h = og * fast_tanh(c);
        A.hd[((step+1)&1)*6272 + bp*196 + j] = h;
      }
    }
    grid.sync();

    // ---- P2: attention + softmax + ctx + u (WGs 0..31); finalize(step-1) on WG 32 ----
    if (wg < 32){
      const int b = wg;
      float* hl2   = scr;          // 196
      float* wcaL  = scr + 200;    // 224
      float* vL    = scr + 424;    // 224
      float* hwda  = scr + 648;    // 224
      float* attnL = scr + 872;    // 256
      float* ctxL  = scr + 1128;   // 320
      float* red   = scr + 1448;   // 4
      const int nxt = (step + 1) & 1;
      if (tid < 196) hl2[tid] = A.hd[nxt*6272 + b*196 + tid];
      if (tid < 224){ wcaL[tid] = A.Wca[tid]; vL[tid] = A.vat[tid]; }
      __syncthreads();
      if (tid < 224){
        const float* wr = A.Wda + (size_t)tid*196;
        float acc = 0.f;
        #pragma unroll 4
        for (int q = 0; q < 196; ++q) acc += hl2[q]*wr[q];
        hwda[tid] = acc;
      } else {
        int l = tid - 224; float acc = 0.f;
        for (int q = l; q < 196; q += 32) acc += hl2[q]*A.Wds[q];
        #pragma unroll
        for (int o=16;o;o>>=1) acc += __shfl_down(acc,o,32);
        if (l==0) A.hWds[(step&1)*32 + b] = acc;
      }
      __syncthreads();
      const int t = tid;
      const int inid = A.in_ids[b*256 + t];
      float sv = -1e30f;
      if (inid != 0){
        const float4* er = (const float4*)(A.encA + (size_t)(b*256 + t)*224);
        float acc = 0.f;
        #pragma unroll 4
        for (int q = 0; q < 56; ++q){
          float4 ev = er[q]; int a0 = 4*q;
          acc += fast_tanh(ev.x + hwda[a0]   + cov*wcaL[a0]  )*vL[a0];
          acc += fast_tanh(ev.y + hwda[a0+1] + cov*wcaL[a0+1])*vL[a0+1];
          acc += fast_tanh(ev.z + hwda[a0+2] + cov*wcaL[a0+2])*vL[a0+2];
          acc += fast_tanh(ev.w + hwda[a0+3] + cov*wcaL[a0+3])*vL[a0+3];
        }
        sv = acc;
      }
      float m  = block_max(sv, red);
      float ex = (inid == 0) ? 0.f : __expf(sv - m);
      float S  = block_sum(ex, red);
      float attn = ex * __builtin_amdgcn_rcpf(S);
      attnL[t] = attn;
      const int ntb = A.tgt[b*100 + step];
      float cpS = block_sum((inid == ntb) ? attn : 0.f, red);
      float mnS = block_sum(fminf(attn, cov), red);
      if (tid == 0){
        A.copyp[(step&1)*32 + b] = cpS;
        clr += mnS;
        if (step == 99) A.cl[b] = clr;
      }
      cov += attn;
      __syncthreads();
      for (int h2 = tid; h2 < 320; h2 += 256){
        const float* ep = A.enc + (size_t)b*256*320 + h2;
        float acc = 0.f;
        #pragma unroll 8
        for (int t2 = 0; t2 < 256; ++t2) acc += attnL[t2]*ep[(size_t)t2*320];
        ctxL[h2] = acc;
      }
      __syncthreads();
      if (tid < 224){
        int g = tid >> 2, ks = tid & 3;
        const float* wr = A.W1 + (size_t)g*516;
        float acc = 0.f;
        for (int q = ks; q < 516; q += 4){
          float hv = (q < 196) ? hl2[q] : ctxL[q - 196];
          acc += hv*wr[q];
        }
        #pragma unroll
        for (int o=2;o;o>>=1) acc += __shfl_down(acc,o,4);
        if (ks == 0) A.u[b*56 + g] = fast_tanh(acc + A.b1[g]);
      } else {
        int l = tid - 224; float acc = 0.f;
        for (int q = l; q < 320; q += 32) acc += ctxL[q]*A.Wcs[q];
        #pragma unroll
        for (int o=16;o;o>>=1) acc += __shfl_down(acc,o,32);
        if (l==0) A.ctxWcs[(step&1)*32 + b] = acc;
      }
    } else if (wg == 32 && step > 0){
      finalize_step(A, step - 1, tid, nll);
    }
    grid.sync();

    // ---- P3: vocab logits partial sum-exp (all 256 WGs) ----
    {
      float* ul  = scr;        // 56
      float* red = scr + 64;   // 4
      const int b3 = wg >> 3, ch = wg & 7;
      if (tid < 56) ul[tid] = A.u[b3*56 + tid];
      __syncthreads();
      const int nt3 = A.tgt[b3*100 + step];
      int idx = nt3 - 2; idx = idx < 0 ? 0 : (idx > 49997 ? 49997 : idx);
      const int vs = ch*6250;
      const int ve = (vs + 6250 < 49998) ? vs + 6250 : 49998;
      float local = 0.f;
      for (int v = vs + tid; v < ve; v += 256){
        const float4* wr = (const float4*)(A.W2 + (size_t)v*56);
        float acc = A.b2[v];
        #pragma unroll
        for (int q = 0; q < 14; ++q){
          float4 wv = wr[q];
          acc += wv.x*ul[4*q] + wv.y*ul[4*q+1] + wv.z*ul[4*q+2] + wv.w*ul[4*q+3];
        }
        if (v == idx) A.zidx[(step&1)*32 + b3] = acc;
        local += __expf(acc);
      }
      float tot = block_sum(local, red);
      if (tid == 0) A.part[(step&1)*256 + b3*8 + ch] = tot;
      __syncthreads();
    }
  }
  grid.sync();
  if (wg == 32){
    finalize_step(A, 99, tid, nll);
    if (tid < 32){
      float n = nll, cv = A.cl[tid];
      #pragma unroll
      for (int o=16;o;o>>=1){ n += __shfl_down(n,o,32); cv += __shfl_down(cv,o,32); }
      if (tid == 0){
        A.out[0] = n;
        A.out[1] = cv;
        A.out[2] = n + 0.75f*cv;
      }
    }
  }
}

// ---------------- host launch ----------------
extern "C" void kernel_launch(void* const* d_in, const int* in_sizes, int n_in,
                              void* d_out, int out_size, void* d_ws, size_t ws_size,
                              hipStream_t stream){
  const int*   in_ids = (const int*)  d_in[0];
  const int*   tgt    = (const int*)  d_in[1];
  const float* emb    = (const float*)d_in[3];
  const float* Wi_f   = (const float*)d_in[4];
  const float* Wh_f   = (const float*)d_in[5];
  const float* bi_f   = (const float*)d_in[6];
  const float* bh_f   = (const float*)d_in[7];
  const float* Wi_b   = (const float*)d_in[8];
  const float* Wh_b   = (const float*)d_in[9];
  const float* bi_b   = (const float*)d_in[10];
  const float* bh_b   = (const float*)d_in[11];
  const float* Weh    = (const float*)d_in[12];
  const float* beh    = (const float*)d_in[13];
  const float* Wec    = (const float*)d_in[14];
  const float* bec    = (const float*)d_in[15];
  const float* Wi_d   = (const float*)d_in[16];
  const float* Wh_d   = (const float*)d_in[17];
  const float* bi_d   = (const float*)d_in[18];
  const float* bh_d   = (const float*)d_in[19];
  const float* Wea    = (const float*)d_in[20];
  const float* bea    = (const float*)d_in[21];
  const float* Wda    = (const float*)d_in[22];
  const float* Wca    = (const float*)d_in[23];
  const float* vat    = (const float*)d_in[24];
  const float* W1     = (const float*)d_in[25];
  const float* b1     = (const float*)d_in[26];
  const float* W2     = (const float*)d_in[27];
  const float* b2     = (const float*)d_in[28];
  const float* Wcs    = (const float*)d_in[29];
  const float* bcs    = (const float*)d_in[30];
  const float* Wds    = (const float*)d_in[31];
  const float* Wes    = (const float*)d_in[32];

  float* ws = (float*)d_ws;
  int* iBase = (int*)(ws + oFEnd);
  int* in_mapped = iBase;
  int* cur_ids   = iBase + 8192;

  prep_kernel<<<32, 256, 0, stream>>>(in_ids, tgt, in_mapped, cur_ids);

  { RGArgs a{nullptr, in_mapped, emb, Wi_f, bi_f, bh_f, ws + oXf, 128, 640};
    rowgemm<<<1024, 256, 8*128*4, stream>>>(a); }
  { RGArgs a{nullptr, in_mapped, emb, Wi_b, bi_b, bh_b, ws + oXb, 128, 640};
    rowgemm<<<1024, 256, 8*128*4, stream>>>(a); }
  { RGArgs a{nullptr, cur_ids, emb, Wi_d, bi_d, bh_d, ws + oXd, 128, 784};
    rowgemm<<<400, 256, 8*128*4, stream>>>(a); }

  es_kernel<<<3200, 64, 0, stream>>>(cur_ids, emb, Wes, ws + oEs);

  { EncArgs ea{ws + oXf, ws + oXb, Wh_f, Wh_b, ws + oHbE, ws + oEnc, ws + oCT};
    void* ka[] = {&ea};
    hipLaunchCooperativeKernel((void*)enc_scan, dim3(40), dim3(256), ka,
                               (unsigned)((5120 + 32*164)*4), stream); }

  mid_kernel<<<32, 256, 0, stream>>>(ws + oEnc, ws + oCT, Weh, beh, Wec, bec,
                                     ws + oHd, ws + oC0);

  { RGArgs a{ws + oEnc, nullptr, emb, Wea, bea, nullptr, ws + oEncA, 320, 224};
    rowgemm<<<1024, 256, 8*320*4, stream>>>(a); }

  { DecArgs da{ws + oXd, Wh_d, ws + oHd, ws + oC0,
               ws + oEnc, ws + oEncA, in_ids, tgt,
               ws + oEs, Wda, Wca, vat,
               W1, b1, W2, b2, Wcs, bcs, Wds,
               ws + oU, ws + oHWds, ws + oCtxW, ws + oCopy, ws + oZidx, ws + oPart,
               ws + oCl, (float*)d_out};
    void* ka[] = {&da};
    hipLaunchCooperativeKernel((void*)dec_scan, dim3(256), dim3(256), ka,
                               (unsigned)((6272 + 6400)*4), stream); }
}

// Round 2
// 18096.284 us; speedup vs baseline: 1.0967x; 1.0967x over previous
//
#include <hip/hip_runtime.h>
#include <hip/hip_cooperative_groups.h>

namespace cg = cooperative_groups;

// ---------------- model dims ----------------
// V=50000 E=128 H=160 D=196 A=224 BN=56, B=32, Tin=256, Ttgt=100
// encoder gates 4H=640, decoder gates 4D=784, 2H=320, D+2H=516, V-END=49998

// ---------------- ws layout (floats) ----------------
constexpr size_t oXf   = 0;                                // 8192 x 640
constexpr size_t oXb   = oXf   + (size_t)8192*640;
constexpr size_t oXd   = oXb   + (size_t)8192*640;         // 3200 x 784
constexpr size_t oEnc  = oXd   + (size_t)3200*784;         // 32 x 256 x 320
constexpr size_t oEncA = oEnc  + (size_t)32*256*320;       // 32 x 256 x 224
constexpr size_t oEs   = oEncA + (size_t)8192*224;         // 3200
constexpr size_t oHbE  = oEs   + 3200;                     // 2 dir x 2 buf x 32 x 160
constexpr size_t oCT   = oHbE  + 2*2*32*160;               // 2 x 32 x 160
constexpr size_t oHd   = oCT   + 2*32*160;                 // 2 x 32 x 196
constexpr size_t oC0   = oHd   + 2*32*196;                 // 32 x 196
constexpr size_t oU    = oC0   + 32*196;                   // 32 x 56
constexpr size_t oHWds = oU    + 32*56;                    // 2 x 32
constexpr size_t oCtxW = oHWds + 64;                       // 2 x 32
constexpr size_t oCopy = oCtxW + 64;                       // 2 x 32
constexpr size_t oZidx = oCopy + 64;                       // 2 x 32
constexpr size_t oPart = oZidx + 64;                       // 2 x 32 x 256 (per-WG partials)
constexpr size_t oCl   = oPart + 2*32*256;                 // 32
constexpr size_t oFEnd = oCl   + 32;
// ints after floats: in_mapped[8192], cur_ids[3200]

// ---------------- device helpers ----------------
__device__ __forceinline__ float fast_tanh(float x){
  float e = __expf(-2.f*fabsf(x));
  float r = (1.f - e) * __builtin_amdgcn_rcpf(1.f + e);
  return copysignf(r, x);
}
__device__ __forceinline__ float sigm(float x){
  return __builtin_amdgcn_rcpf(1.f + __expf(-x));
}
__device__ __forceinline__ float block_sum(float v, float* red){
  #pragma unroll
  for (int o=32;o;o>>=1) v += __shfl_down(v,o);
  if ((threadIdx.x&63)==0) red[threadIdx.x>>6] = v;
  __syncthreads();
  v = red[0]+red[1]+red[2]+red[3];
  __syncthreads();
  return v;
}
__device__ __forceinline__ float block_max(float v, float* red){
  #pragma unroll
  for (int o=32;o;o>>=1) v = fmaxf(v,__shfl_down(v,o));
  if ((threadIdx.x&63)==0) red[threadIdx.x>>6] = v;
  __syncthreads();
  v = fmaxf(fmaxf(red[0],red[1]),fmaxf(red[2],red[3]));
  __syncthreads();
  return v;
}

// ---------------- prep: id mapping ----------------
__global__ void prep_kernel(const int* __restrict__ in_ids, const int* __restrict__ tgt,
                            int* __restrict__ in_mapped, int* __restrict__ cur_ids){
  int i = blockIdx.x*256 + threadIdx.x;
  if (i < 8192){
    int t = i >> 5, b = i & 31;
    int id = in_ids[b*256 + t];
    in_mapped[i] = (id >= 50000) ? 3 : id;
  }
  if (i < 3200){
    int k = i >> 5, b = i & 31;
    int id = (k == 0) ? 1 : tgt[b*100 + (k-1)];
    cur_ids[i] = (id >= 50000) ? 3 : id;
  }
}

// ---------------- generic row GEMM: out[r][g] = bias(g) + sum_k src(r,k)*W[g][k] ----------------
struct RGArgs{ const float* src; const int* gid; const float* emb; const float* W;
               const float* bias1; const float* bias2; float* out; int K; int N; };
__global__ void __launch_bounds__(256) rowgemm(RGArgs a){
  extern __shared__ float rl[];   // 8 x K
  const int tid = threadIdx.x;
  const int K = a.K, N = a.N;
  const size_t r0 = (size_t)blockIdx.x*8;
  for (int i = tid; i < 8*K; i += 256){
    int r = i / K, k = i - r*K;
    const float* srow = a.gid ? (a.emb + (size_t)a.gid[r0+r]*128)
                              : (a.src + (r0+r)*(size_t)K);
    rl[i] = srow[k];
  }
  __syncthreads();
  for (int g = tid; g < N; g += 256){
    const float* wr = a.W + (size_t)g*K;
    float acc[8];
    #pragma unroll
    for (int r=0;r<8;r++) acc[r]=0.f;
    for (int k=0;k<K;k+=4){
      float4 wv = *(const float4*)(wr+k);
      #pragma unroll
      for (int r=0;r<8;r++){
        float4 xv = *(const float4*)(rl + r*K + k);
        acc[r] += wv.x*xv.x + wv.y*xv.y + wv.z*xv.z + wv.w*xv.w;
      }
    }
    float bias = a.bias1[g] + (a.bias2 ? a.bias2[g] : 0.f);
    #pragma unroll
    for (int r=0;r<8;r++) a.out[(r0+r)*(size_t)N + g] = acc[r] + bias;
  }
}

// ---------------- es[r] = emb[gid[r]] . Wes ----------------
__global__ void es_kernel(const int* __restrict__ gid, const float* __restrict__ emb,
                          const float* __restrict__ Wes, float* __restrict__ es){
  int r = blockIdx.x, l = threadIdx.x;  // 64 threads = 1 wave
  const float* e = emb + (size_t)gid[r]*128;
  float acc = e[l]*Wes[l] + e[l+64]*Wes[l+64];
  #pragma unroll
  for (int o=32;o;o>>=1) acc += __shfl_down(acc,o);
  if (l==0) es[r] = acc;
}

// ---------------- encoder bidirectional LSTM scan (cooperative, grid=40) ----------------
struct EncArgs{ const float* Xf; const float* Xb; const float* Whf; const float* Whb;
                float* hbuf; float* enc; float* cT; };
__global__ void __launch_bounds__(256) enc_scan(EncArgs a){
  extern __shared__ float sm[];
  float* Wl = sm;           // [gate*8+jl][160]  = 5120
  float* hl = sm + 5120;    // [32][164]          = 5248
  const int wg = blockIdx.x;
  const int dir = wg/20, jwg = wg%20;
  const int tid = threadIdx.x;
  const int b = tid & 31, jl = tid >> 5;
  const int j = jwg*8 + jl;   // < 160 always
  const float* Wh = dir ? a.Whb : a.Whf;
  const float* X  = dir ? a.Xb  : a.Xf;
  float* hb = a.hbuf + dir*(2*32*160);
  for (int i = tid; i < 32*160; i += 256){
    int row = i/160, k = i - row*160;
    int gate = row >> 3, jj = row & 7;
    Wl[i] = Wh[((size_t)(gate*160 + jwg*8 + jj))*160 + k];
  }
  for (int i = tid; i < 32*160; i += 256) hb[i] = 0.f;
  float c = 0.f;
  const float4* w0 = (const float4*)(Wl + (0*8+jl)*160);
  const float4* w1 = (const float4*)(Wl + (1*8+jl)*160);
  const float4* w2 = (const float4*)(Wl + (2*8+jl)*160);
  const float4* w3 = (const float4*)(Wl + (3*8+jl)*160);
  cg::grid_group grid = cg::this_grid();
  grid.sync();
  for (int t = 0; t < 256; ++t){
    const int cur = t & 1;
    const int trow = dir ? (255 - t) : t;
    const float* xr = X + ((size_t)trow*32 + b)*640 + j;
    float g0 = xr[0], g1 = xr[160], g2 = xr[320], g3 = xr[480];
    __syncthreads();
    for (int i = tid; i < 32*160; i += 256){
      int bb = i/160, k = i - bb*160;
      hl[bb*164 + k] = hb[cur*5120 + i];
    }
    __syncthreads();
    const float4* hr = (const float4*)(hl + b*164);
    #pragma unroll 4
    for (int q = 0; q < 40; ++q){
      float4 hv = hr[q];
      float4 a0 = w0[q], a1 = w1[q], a2 = w2[q], a3 = w3[q];
      g0 += hv.x*a0.x + hv.y*a0.y + hv.z*a0.z + hv.w*a0.w;
      g1 += hv.x*a1.x + hv.y*a1.y + hv.z*a1.z + hv.w*a1.w;
      g2 += hv.x*a2.x + hv.y*a2.y + hv.z*a2.z + hv.w*a2.w;
      g3 += hv.x*a3.x + hv.y*a3.y + hv.z*a3.z + hv.w*a3.w;
    }
    float ig = sigm(g0), fg = sigm(g1), gc = fast_tanh(g2), og = sigm(g3);
    c = fg*c + ig*gc;
    float h = og * fast_tanh(c);
    hb[((t+1)&1)*5120 + b*160 + j] = h;
    a.enc[((size_t)b*256 + trow)*320 + dir*160 + j] = h;
    grid.sync();
  }
  a.cT[dir*5120 + b*160 + j] = c;
}

// ---------------- mid: h0/c0 projections ----------------
__global__ void mid_kernel(const float* __restrict__ enc, const float* __restrict__ cT,
                           const float* __restrict__ Weh, const float* __restrict__ beh,
                           const float* __restrict__ Wec, const float* __restrict__ bec,
                           float* __restrict__ h0, float* __restrict__ c0){
  __shared__ float hc[320], cc[320];
  int b = blockIdx.x, tid = threadIdx.x;
  if (tid < 160){
    hc[tid]     = enc[((size_t)b*256 + 255)*320 + tid];
    hc[160+tid] = enc[((size_t)b*256 + 0)*320 + 160 + tid];
    cc[tid]     = cT[b*160 + tid];
    cc[160+tid] = cT[5120 + b*160 + tid];
  }
  __syncthreads();
  for (int g = tid; g < 196; g += 256){
    const float* w1 = Weh + (size_t)g*320;
    const float* w2 = Wec + (size_t)g*320;
    float a1 = beh[g], a2 = bec[g];
    for (int k = 0; k < 320; ++k){ a1 += hc[k]*w1[k]; a2 += cc[k]*w2[k]; }
    h0[b*196 + g] = a1;
    c0[b*196 + g] = a2;
  }
}

// ---------------- decoder scan (cooperative, grid=256) ----------------
struct DecArgs{
  const float* Xd; const float* Whd; float* hd; const float* c0;
  const float* enc; const float* encA; const int* in_ids; const int* tgt;
  const float* es; const float* Wda; const float* Wca; const float* vat;
  const float* W1; const float* b1; const float* W2; const float* b2;
  const float* Wcs; const float* bcs; const float* Wds;
  float* u; float* hWds; float* ctxWcs; float* copyp; float* zidx; float* part;
  float* cl; float* out;
};

// finalize step s: runs on WG 32 with all 256 threads; scrF = 256-float LDS scratch
__device__ __forceinline__ void finalize_step(const DecArgs& A, int s, int tid,
                                              float* scrF, float& nll){
  const int sl = s & 1;
  const int b = tid & 31, seg = tid >> 5;
  float ps = 0.f;
  const float* pp = A.part + sl*8192 + b*256 + seg*32;
  #pragma unroll
  for (int k = 0; k < 32; ++k) ps += pp[k];
  scrF[seg*32 + b] = ps;
  __syncthreads();
  if (tid < 32){
    float se = 0.f;
    #pragma unroll
    for (int k = 0; k < 8; ++k) se += scrF[k*32 + tid];
    int nt2 = A.tgt[tid*100 + s];
    float xg = A.ctxWcs[sl*32+tid] + A.bcs[0] + A.hWds[sl*32+tid] + A.es[(size_t)s*32 + tid];
    float pg = 1.f/(1.f + __expf(-xg));
    float genp = (nt2 >= 2 && nt2 < 50000) ? (__expf(A.zidx[sl*32+tid]) / se) : 0.f;
    float p = pg*genp + (1.f - pg)*A.copyp[sl*32+tid];
    nll += -logf(p + 1e-9f);
  }
  __syncthreads();
}

__global__ void __launch_bounds__(256) dec_scan(DecArgs A){
  extern __shared__ float sm[];
  float* Wl  = sm;          // 4*8*196 = 6272 (persistent, WGs 0..24)
  float* scr = sm + 6272;   // 6400 scratch (all phases)
  const int wg = blockIdx.x, tid = threadIdx.x;
  cg::grid_group grid = cg::this_grid();

  const int bp = tid & 31, jl = tid >> 5;
  const int j = wg*8 + jl;                 // valid only for wg<25
  float c = 0.f;                           // decoder LSTM cell (wg<25)
  if (wg < 25){
    for (int i = tid; i < 32*196; i += 256){
      int row = i/196, k = i - row*196;
      int gate = row >> 3, jj = row & 7;
      int jg = wg*8 + jj;
      Wl[i] = (jg < 196) ? A.Whd[((size_t)(gate*196 + jg))*196 + k] : 0.f;
    }
    if (j < 196) c = A.c0[bp*196 + j];
  }
  float cov = 0.f;    // coverage (wg<32, thread t=tid)
  float clr = 0.f;    // coverage-loss accumulator (wg<32, tid 0)
  float nll = 0.f;    // nll accumulator (wg==32, tid<32)

  const float4* w0 = (const float4*)(Wl + (0*8+jl)*196);
  const float4* w1 = (const float4*)(Wl + (1*8+jl)*196);
  const float4* w2 = (const float4*)(Wl + (2*8+jl)*196);
  const float4* w3 = (const float4*)(Wl + (3*8+jl)*196);

  for (int step = 0; step < 100; ++step){
    // ---- P1: decoder LSTM step (WGs 0..24) ----
    if (wg < 25){
      const int cur = step & 1;
      float g0=0.f,g1=0.f,g2=0.f,g3=0.f;
      if (j < 196){
        const float* xr = A.Xd + ((size_t)step*32 + bp)*784 + j;
        g0 = xr[0]; g1 = xr[196]; g2 = xr[392]; g3 = xr[588];
      }
      __syncthreads();
      for (int i = tid; i < 32*196; i += 256){
        int bb = i/196, k = i - bb*196;
        scr[bb*200 + k] = A.hd[cur*6272 + i];
      }
      __syncthreads();
      if (j < 196){
        const float4* hr = (const float4*)(scr + bp*200);
        #pragma unroll 7
        for (int q = 0; q < 49; ++q){
          float4 hv = hr[q];
          float4 a0 = w0[q], a1 = w1[q], a2 = w2[q], a3 = w3[q];
          g0 += hv.x*a0.x + hv.y*a0.y + hv.z*a0.z + hv.w*a0.w;
          g1 += hv.x*a1.x + hv.y*a1.y + hv.z*a1.z + hv.w*a1.w;
          g2 += hv.x*a2.x + hv.y*a2.y + hv.z*a2.z + hv.w*a2.w;
          g3 += hv.x*a3.x + hv.y*a3.y + hv.z*a3.z + hv.w*a3.w;
        }
        float ig = sigm(g0), fg = sigm(g1), gc = fast_tanh(g2), og = sigm(g3);
        c = fg*c + ig*gc;
        float h = og * fast_tanh(c);
        A.hd[((step+1)&1)*6272 + bp*196 + j] = h;
      }
    }
    grid.sync();

    // ---- P2: attention + softmax + ctx + u (WGs 0..31); finalize(step-1) on WG 32 ----
    if (wg < 32){
      const int b = wg;
      float* hl2   = scr;          // 196
      float* wcaL  = scr + 200;    // 224
      float* vL    = scr + 424;    // 224
      float* hwda  = scr + 648;    // 224
      float* attnL = scr + 872;    // 256
      float* ctxL  = scr + 1128;   // 320
      float* red   = scr + 1448;   // 4
      const int nxt = (step + 1) & 1;
      if (tid < 196) hl2[tid] = A.hd[nxt*6272 + b*196 + tid];
      if (tid < 224){ wcaL[tid] = A.Wca[tid]; vL[tid] = A.vat[tid]; }
      __syncthreads();
      if (tid < 224){
        const float* wr = A.Wda + (size_t)tid*196;
        float acc = 0.f;
        #pragma unroll 4
        for (int q = 0; q < 196; ++q) acc += hl2[q]*wr[q];
        hwda[tid] = acc;
      } else {
        int l = tid - 224; float acc = 0.f;
        for (int q = l; q < 196; q += 32) acc += hl2[q]*A.Wds[q];
        #pragma unroll
        for (int o=16;o;o>>=1) acc += __shfl_down(acc,o,32);
        if (l==0) A.hWds[(step&1)*32 + b] = acc;
      }
      __syncthreads();
      const int t = tid;
      const int inid = A.in_ids[b*256 + t];
      float sv = -1e30f;
      if (inid != 0){
        const float4* er = (const float4*)(A.encA + (size_t)(b*256 + t)*224);
        float acc = 0.f;
        #pragma unroll 4
        for (int q = 0; q < 56; ++q){
          float4 ev = er[q]; int a0 = 4*q;
          acc += fast_tanh(ev.x + hwda[a0]   + cov*wcaL[a0]  )*vL[a0];
          acc += fast_tanh(ev.y + hwda[a0+1] + cov*wcaL[a0+1])*vL[a0+1];
          acc += fast_tanh(ev.z + hwda[a0+2] + cov*wcaL[a0+2])*vL[a0+2];
          acc += fast_tanh(ev.w + hwda[a0+3] + cov*wcaL[a0+3])*vL[a0+3];
        }
        sv = acc;
      }
      float m  = block_max(sv, red);
      float ex = (inid == 0) ? 0.f : __expf(sv - m);
      float S  = block_sum(ex, red);
      float attn = ex * __builtin_amdgcn_rcpf(S);
      attnL[t] = attn;
      const int ntb = A.tgt[b*100 + step];
      float cpS = block_sum((inid == ntb) ? attn : 0.f, red);
      float mnS = block_sum(fminf(attn, cov), red);
      if (tid == 0){
        A.copyp[(step&1)*32 + b] = cpS;
        clr += mnS;
        if (step == 99) A.cl[b] = clr;
      }
      cov += attn;
      __syncthreads();
      for (int h2 = tid; h2 < 320; h2 += 256){
        const float* ep = A.enc + (size_t)b*256*320 + h2;
        float acc = 0.f;
        #pragma unroll 8
        for (int t2 = 0; t2 < 256; ++t2) acc += attnL[t2]*ep[(size_t)t2*320];
        ctxL[h2] = acc;
      }
      __syncthreads();
      if (tid < 224){
        int g = tid >> 2, ks = tid & 3;
        const float* wr = A.W1 + (size_t)g*516;
        float acc = 0.f;
        for (int q = ks; q < 516; q += 4){
          float hv = (q < 196) ? hl2[q] : ctxL[q - 196];
          acc += hv*wr[q];
        }
        #pragma unroll
        for (int o=2;o;o>>=1) acc += __shfl_down(acc,o,4);
        if (ks == 0) A.u[b*56 + g] = fast_tanh(acc + A.b1[g]);
      } else {
        int l = tid - 224; float acc = 0.f;
        for (int q = l; q < 320; q += 32) acc += ctxL[q]*A.Wcs[q];
        #pragma unroll
        for (int o=16;o;o>>=1) acc += __shfl_down(acc,o,32);
        if (l==0) A.ctxWcs[(step&1)*32 + b] = acc;
      }
    } else if (wg == 32 && step > 0){
      finalize_step(A, step - 1, tid, scr, nll);
    }
    grid.sync();

    // ---- P3: vocab partial sum-exp — each WG owns a ~196-row W2 chunk, all 32 batches ----
    {
      float* ulL  = scr;                 // 32*56 = 1792
      float* redW = scr + 1792;          // 4 waves * 32 = 128
      int*   idxL = (int*)(scr + 1920);  // 32
      for (int i = tid; i < 1792; i += 256) ulL[i] = A.u[i];
      if (tid < 32){
        int nt3 = A.tgt[tid*100 + step];
        int ix = nt3 - 2; ix = ix < 0 ? 0 : (ix > 49997 ? 49997 : ix);
        idxL[tid] = ix;
      }
      __syncthreads();
      const int vs = (wg*49998) >> 8;
      const int ve = ((wg+1)*49998) >> 8;
      const int v  = vs + tid;
      const bool valid = v < ve;
      const int vc = valid ? v : 49997;
      const float4* wr = (const float4*)(A.W2 + (size_t)vc*56);
      float4 w2r[14];
      #pragma unroll
      for (int q = 0; q < 14; ++q) w2r[q] = wr[q];
      const float b2v = A.b2[vc];
      float ex[32];
      #pragma unroll
      for (int bb = 0; bb < 32; ++bb){
        const float4* uv = (const float4*)(ulL + bb*56);
        float z = b2v;
        #pragma unroll
        for (int q = 0; q < 14; ++q){
          float4 u4 = uv[q];
          z += w2r[q].x*u4.x + w2r[q].y*u4.y + w2r[q].z*u4.z + w2r[q].w*u4.w;
        }
        if (valid && v == idxL[bb]) A.zidx[(step&1)*32 + bb] = z;
        ex[bb] = valid ? __expf(z) : 0.f;
      }
      // per-wave reduce of each ex[b], lane 0 holds the sum
      #pragma unroll
      for (int bb = 0; bb < 32; ++bb){
        float s = ex[bb];
        #pragma unroll
        for (int o = 32; o; o >>= 1) s += __shfl_down(s, o);
        ex[bb] = s;
      }
      const int lane = tid & 63, wv = tid >> 6;
      if (lane == 0){
        #pragma unroll
        for (int bb = 0; bb < 32; ++bb) redW[wv*32 + bb] = ex[bb];
      }
      __syncthreads();
      if (tid < 32){
        float tot = redW[tid] + redW[32+tid] + redW[64+tid] + redW[96+tid];
        A.part[(step&1)*8192 + tid*256 + wg] = tot;
      }
      __syncthreads();
    }
  }
  grid.sync();
  if (wg == 32){
    finalize_step(A, 99, tid, scr, nll);
    if (tid < 32){
      float n = nll, cv = A.cl[tid];
      #pragma unroll
      for (int o=16;o;o>>=1){ n += __shfl_down(n,o,32); cv += __shfl_down(cv,o,32); }
      if (tid == 0){
        A.out[0] = n;
        A.out[1] = cv;
        A.out[2] = n + 0.75f*cv;
      }
    }
  }
}

// ---------------- host launch ----------------
extern "C" void kernel_launch(void* const* d_in, const int* in_sizes, int n_in,
                              void* d_out, int out_size, void* d_ws, size_t ws_size,
                              hipStream_t stream){
  const int*   in_ids = (const int*)  d_in[0];
  const int*   tgt    = (const int*)  d_in[1];
  const float* emb    = (const float*)d_in[3];
  const float* Wi_f   = (const float*)d_in[4];
  const float* Wh_f   = (const float*)d_in[5];
  const float* bi_f   = (const float*)d_in[6];
  const float* bh_f   = (const float*)d_in[7];
  const float* Wi_b   = (const float*)d_in[8];
  const float* Wh_b   = (const float*)d_in[9];
  const float* bi_b   = (const float*)d_in[10];
  const float* bh_b   = (const float*)d_in[11];
  const float* Weh    = (const float*)d_in[12];
  const float* beh    = (const float*)d_in[13];
  const float* Wec    = (const float*)d_in[14];
  const float* bec    = (const float*)d_in[15];
  const float* Wi_d   = (const float*)d_in[16];
  const float* Wh_d   = (const float*)d_in[17];
  const float* bi_d   = (const float*)d_in[18];
  const float* bh_d   = (const float*)d_in[19];
  const float* Wea    = (const float*)d_in[20];
  const float* bea    = (const float*)d_in[21];
  const float* Wda    = (const float*)d_in[22];
  const float* Wca    = (const float*)d_in[23];
  const float* vat    = (const float*)d_in[24];
  const float* W1     = (const float*)d_in[25];
  const float* b1     = (const float*)d_in[26];
  const float* W2     = (const float*)d_in[27];
  const float* b2     = (const float*)d_in[28];
  const float* Wcs    = (const float*)d_in[29];
  const float* bcs    = (const float*)d_in[30];
  const float* Wds    = (const float*)d_in[31];
  const float* Wes    = (const float*)d_in[32];

  float* ws = (float*)d_ws;
  int* iBase = (int*)(ws + oFEnd);
  int* in_mapped = iBase;
  int* cur_ids   = iBase + 8192;

  prep_kernel<<<32, 256, 0, stream>>>(in_ids, tgt, in_mapped, cur_ids);

  { RGArgs a{nullptr, in_mapped, emb, Wi_f, bi_f, bh_f, ws + oXf, 128, 640};
    rowgemm<<<1024, 256, 8*128*4, stream>>>(a); }
  { RGArgs a{nullptr, in_mapped, emb, Wi_b, bi_b, bh_b, ws + oXb, 128, 640};
    rowgemm<<<1024, 256, 8*128*4, stream>>>(a); }
  { RGArgs a{nullptr, cur_ids, emb, Wi_d, bi_d, bh_d, ws + oXd, 128, 784};
    rowgemm<<<400, 256, 8*128*4, stream>>>(a); }

  es_kernel<<<3200, 64, 0, stream>>>(cur_ids, emb, Wes, ws + oEs);

  { EncArgs ea{ws + oXf, ws + oXb, Wh_f, Wh_b, ws + oHbE, ws + oEnc, ws + oCT};
    void* ka[] = {&ea};
    hipLaunchCooperativeKernel((void*)enc_scan, dim3(40), dim3(256), ka,
                               (unsigned)((5120 + 32*164)*4), stream); }

  mid_kernel<<<32, 256, 0, stream>>>(ws + oEnc, ws + oCT, Weh, beh, Wec, bec,
                                     ws + oHd, ws + oC0);

  { RGArgs a{ws + oEnc, nullptr, emb, Wea, bea, nullptr, ws + oEncA, 320, 224};
    rowgemm<<<1024, 256, 8*320*4, stream>>>(a); }

  { DecArgs da{ws + oXd, Wh_d, ws + oHd, ws + oC0,
               ws + oEnc, ws + oEncA, in_ids, tgt,
               ws + oEs, Wda, Wca, vat,
               W1, b1, W2, b2, Wcs, bcs, Wds,
               ws + oU, ws + oHWds, ws + oCtxW, ws + oCopy, ws + oZidx, ws + oPart,
               ws + oCl, (float*)d_out};
    void* ka[] = {&da};
    hipLaunchCooperativeKernel((void*)dec_scan, dim3(256), dim3(256), ka,
                               (unsigned)((6272 + 6400)*4), stream); }
}

// Round 3
// 5885.027 us; speedup vs baseline: 3.3723x; 3.0750x over previous
//
#include <hip/hip_runtime.h>

#define MSCOPE __HIP_MEMORY_SCOPE_AGENT

// ---------------- model dims ----------------
// V=50000 E=128 H=160 D=196 A=224 BN=56, B=32, Tin=256, Ttgt=100
// encoder gates 4H=640, decoder gates 4D=784, 2H=320, D+2H=516, V-END=49998

// ---------------- ws float layout ----------------
constexpr size_t oXf   = 0;                                // 8192 x 640 (enc phase)
constexpr size_t oXb   = oXf   + (size_t)8192*640;
constexpr size_t oXd   = oXb   + (size_t)8192*640;         // 3200 x 784
constexpr size_t oHenc = oXd   + (size_t)3200*784;         // 2 x 256 x (32*160)
constexpr size_t oEncA = oHenc + (size_t)2*256*5120;       // 8192 x 224
constexpr size_t oEs   = oEncA + (size_t)8192*224;         // 3200
constexpr size_t oCT   = oEs   + 3200;                     // 2 x 5120
constexpr size_t oH0   = oCT   + 10240;                    // 32 x 196
constexpr size_t oC0   = oH0   + 6272;                     // 32 x 196
constexpr size_t oHWdsAll = oC0 + 6272;                    // 100 x 32
constexpr size_t oCtxWAll = oHWdsAll + 3200;
constexpr size_t oCopyAll = oCtxWAll + 3200;
constexpr size_t oZidxAll = oCopyAll + 3200;
constexpr size_t oClAll   = oZidxAll + 3200;               // 32
constexpr size_t oNllWg   = oClAll + 32;                   // 224
constexpr size_t oFEnd    = oNllWg + 224;
// dec-phase overlays on the (dead) Xf region:
constexpr size_t oHdAll   = 0;                             // 100 x 32 x 196
constexpr size_t oUAll    = oHdAll + (size_t)100*6272;     // 100 x 32 x 56
constexpr size_t oPartAll = oUAll  + (size_t)100*1792;     // 100 x 32 x 224
// ints after floats: in_mapped[8192], cur_ids[3200], flags[23232]
constexpr int fEnc  = 0;          // 2*256*32
constexpr int fLstm = 16384;      // 100*32
constexpr int fP2   = 19584;      // 100*32
constexpr int fP3   = 22784;      // 224
constexpr int fFin  = 23008;      // 224
constexpr int fEnd  = 23232;

// ---------------- helpers ----------------
__device__ __forceinline__ float fast_tanh(float x){
  float e = __expf(-2.f*fabsf(x));
  float r = (1.f - e) * __builtin_amdgcn_rcpf(1.f + e);
  return copysignf(r, x);
}
__device__ __forceinline__ float sigm(float x){
  return __builtin_amdgcn_rcpf(1.f + __expf(-x));
}
__device__ __forceinline__ float aload(const float* p){
  return __hip_atomic_load(const_cast<float*>(p), __ATOMIC_RELAXED, MSCOPE);
}
template<bool ACQ>
__device__ __forceinline__ void wait_slots(unsigned* slots, int n, int tid){
  if (tid < 64){
    for(;;){
      bool miss = false;
      for (int i = tid; i < n; i += 64)
        if (__hip_atomic_load(&slots[i], __ATOMIC_RELAXED, MSCOPE) == 0u) miss = true;
      if (__ballot(miss) == 0ULL) break;
      __builtin_amdgcn_s_sleep(2);
    }
    if (ACQ) (void)__hip_atomic_load(&slots[0], __ATOMIC_ACQUIRE, MSCOPE);
  }
  __syncthreads();
}
__device__ __forceinline__ void set_slot(unsigned* slot){
  __hip_atomic_store(slot, 1u, __ATOMIC_RELEASE, MSCOPE);
}
__device__ __forceinline__ float block_sum(float v, float* red){
  #pragma unroll
  for (int o=32;o;o>>=1) v += __shfl_down(v,o);
  if ((threadIdx.x&63)==0) red[threadIdx.x>>6] = v;
  __syncthreads();
  v = red[0]+red[1]+red[2]+red[3];
  __syncthreads();
  return v;
}

// ---------------- prep: id mapping + flag zeroing ----------------
__global__ void prep_kernel(const int* __restrict__ in_ids, const int* __restrict__ tgt,
                            int* __restrict__ in_mapped, int* __restrict__ cur_ids,
                            unsigned* __restrict__ flags){
  int i = blockIdx.x*256 + threadIdx.x;
  if (i < 8192){
    int t = i >> 5, b = i & 31;
    int id = in_ids[b*256 + t];
    in_mapped[i] = (id >= 50000) ? 3 : id;
  }
  if (i < 3200){
    int k = i >> 5, b = i & 31;
    int id = (k == 0) ? 1 : tgt[b*100 + (k-1)];
    cur_ids[i] = (id >= 50000) ? 3 : id;
  }
  if (i < fEnd) flags[i] = 0u;
}

// ---------------- row GEMM: out[r][g] = bias(g) + sum_k src(r,k)*W[g][k] ----------------
struct RGArgs{ const float* src; const int* gid; const float* emb; const float* W;
               const float* bias1; const float* bias2; float* out; int K; int N; };
__global__ void __launch_bounds__(256) rowgemm(RGArgs a){
  extern __shared__ float rl[];   // 8 x K
  const int tid = threadIdx.x;
  const int K = a.K, N = a.N;
  const size_t r0 = (size_t)blockIdx.x*8;
  for (int i = tid; i < 8*K; i += 256){
    int r = i / K, k = i - r*K;
    const float* srow = a.gid ? (a.emb + (size_t)a.gid[r0+r]*128)
                              : (a.src + (r0+r)*(size_t)K);
    rl[i] = srow[k];
  }
  __syncthreads();
  for (int g = tid; g < N; g += 256){
    const float* wr = a.W + (size_t)g*K;
    float acc[8];
    #pragma unroll
    for (int r=0;r<8;r++) acc[r]=0.f;
    for (int k=0;k<K;k+=4){
      float4 wv = *(const float4*)(wr+k);
      #pragma unroll
      for (int r=0;r<8;r++){
        float4 xv = *(const float4*)(rl + r*K + k);
        acc[r] += wv.x*xv.x + wv.y*xv.y + wv.z*xv.z + wv.w*xv.w;
      }
    }
    float bias = a.bias1[g] + (a.bias2 ? a.bias2[g] : 0.f);
    #pragma unroll
    for (int r=0;r<8;r++) a.out[(r0+r)*(size_t)N + g] = acc[r] + bias;
  }
}

// ---------------- es[r] = emb[gid[r]] . Wes ----------------
__global__ void es_kernel(const int* __restrict__ gid, const float* __restrict__ emb,
                          const float* __restrict__ Wes, float* __restrict__ es){
  int r = blockIdx.x, l = threadIdx.x;
  const float* e = emb + (size_t)gid[r]*128;
  float acc = e[l]*Wes[l] + e[l+64]*Wes[l+64];
  #pragma unroll
  for (int o=32;o;o>>=1) acc += __shfl_down(acc,o);
  if (l==0) es[r] = acc;
}

// ---------------- encoder bidirectional LSTM scan (flags, grid=40) ----------------
struct EncArgs{ const float* Xf; const float* Xb; const float* Whf; const float* Whb;
                float* henc; float* cT; unsigned* done; };
__global__ void __launch_bounds__(256) enc_scan(EncArgs a){
  extern __shared__ float sm[];
  float* Wl = sm;           // 5120
  float* hl = sm + 5120;    // 32 x 164
  const int wg = blockIdx.x;
  const int dir = wg/20, jwg = wg%20;
  const int tid = threadIdx.x;
  const int b = tid & 31, jl = tid >> 5;
  const int j = jwg*8 + jl;
  const float* Wh = dir ? a.Whb : a.Whf;
  const float* X  = dir ? a.Xb  : a.Xf;
  float* H = a.henc + (size_t)dir*256*5120;
  unsigned* done = a.done + dir*256*32;
  for (int i = tid; i < 32*160; i += 256){
    int row = i/160, k = i - row*160;
    int gate = row >> 3, jj = row & 7;
    Wl[i] = Wh[((size_t)(gate*160 + jwg*8 + jj))*160 + k];
  }
  float c = 0.f;
  const float4* w0 = (const float4*)(Wl + (0*8+jl)*160);
  const float4* w1 = (const float4*)(Wl + (1*8+jl)*160);
  const float4* w2 = (const float4*)(Wl + (2*8+jl)*160);
  const float4* w3 = (const float4*)(Wl + (3*8+jl)*160);
  __syncthreads();
  for (int t = 0; t < 256; ++t){
    const int trow = dir ? (255 - t) : t;
    const float* xr = X + ((size_t)trow*32 + b)*640 + j;
    float g0 = xr[0], g1 = xr[160], g2 = xr[320], g3 = xr[480];
    if (t > 0){
      wait_slots<true>(done + (t-1)*32, 20, tid);
      const int tprev = dir ? (256 - t) : (t-1);
      const float4* hp = (const float4*)(H + (size_t)tprev*5120);
      for (int i4 = tid; i4 < 1280; i4 += 256){
        int bb = i4/40, k4 = i4 - bb*40;
        ((float4*)hl)[bb*41 + k4] = hp[i4];
      }
    } else {
      for (int i = tid; i < 5120; i += 256){ int bb=i/160,k=i-bb*160; hl[bb*164+k]=0.f; }
    }
    __syncthreads();
    const float4* hr = (const float4*)(hl + b*164);
    #pragma unroll 4
    for (int q = 0; q < 40; ++q){
      float4 hv = hr[q];
      float4 a0 = w0[q], a1 = w1[q], a2 = w2[q], a3 = w3[q];
      g0 += hv.x*a0.x + hv.y*a0.y + hv.z*a0.z + hv.w*a0.w;
      g1 += hv.x*a1.x + hv.y*a1.y + hv.z*a1.z + hv.w*a1.w;
      g2 += hv.x*a2.x + hv.y*a2.y + hv.z*a2.z + hv.w*a2.w;
      g3 += hv.x*a3.x + hv.y*a3.y + hv.z*a3.z + hv.w*a3.w;
    }
    float ig = sigm(g0), fg = sigm(g1), gc = fast_tanh(g2), og = sigm(g3);
    c = fg*c + ig*gc;
    float h = og * fast_tanh(c);
    H[(size_t)trow*5120 + b*160 + j] = h;
    __syncthreads();                       // drains vmcnt: stores in L2
    if (tid == 0) set_slot(done + t*32 + jwg);
  }
  a.cT[dir*5120 + b*160 + j] = c;
}

// ---------------- mid: h0/c0 projections ----------------
__global__ void mid_kernel(const float* __restrict__ henc, const float* __restrict__ cT,
                           const float* __restrict__ Weh, const float* __restrict__ beh,
                           const float* __restrict__ Wec, const float* __restrict__ bec,
                           float* __restrict__ h0, float* __restrict__ c0){
  __shared__ float hc[320], cc[320];
  int b = blockIdx.x, tid = threadIdx.x;
  if (tid < 160){
    hc[tid]     = henc[(size_t)255*5120 + b*160 + tid];        // fwd final
    hc[160+tid] = henc[(size_t)256*5120 + b*160 + tid];        // bwd final (t_orig=0)
    cc[tid]     = cT[b*160 + tid];
    cc[160+tid] = cT[5120 + b*160 + tid];
  }
  __syncthreads();
  for (int g = tid; g < 196; g += 256){
    const float* w1 = Weh + (size_t)g*320;
    const float* w2 = Wec + (size_t)g*320;
    float a1 = beh[g], a2 = bec[g];
    for (int k = 0; k < 320; ++k){ a1 += hc[k]*w1[k]; a2 += cc[k]*w2[k]; }
    h0[b*196 + g] = a1;
    c0[b*196 + g] = a2;
  }
}

// ---------------- encA = [hf;hb] @ Wea.T + bea ----------------
__global__ void __launch_bounds__(256) encA_gemm(const float* __restrict__ henc,
                 const float* __restrict__ Wea, const float* __restrict__ bea,
                 float* __restrict__ encA){
  __shared__ float rl[8*320];
  const int tid = threadIdx.x;
  const size_t r0 = (size_t)blockIdx.x*8;
  for (int i = tid; i < 8*320; i += 256){
    int r = i/320, k = i - r*320;
    size_t row = r0 + r; int b = (int)(row >> 8), t = (int)(row & 255);
    rl[i] = (k < 160) ? henc[(size_t)t*5120 + b*160 + k]
                      : henc[(size_t)(256+t)*5120 + b*160 + (k-160)];
  }
  __syncthreads();
  for (int g = tid; g < 224; g += 256){
    const float* wr = Wea + (size_t)g*320;
    float acc[8];
    #pragma unroll
    for (int r=0;r<8;r++) acc[r]=0.f;
    for (int k=0;k<320;k+=4){
      float4 wv = *(const float4*)(wr+k);
      #pragma unroll
      for (int r=0;r<8;r++){
        float4 xv = *(const float4*)(rl + r*320 + k);
        acc[r] += wv.x*xv.x + wv.y*xv.y + wv.z*xv.z + wv.w*xv.w;
      }
    }
    float bias = bea[g];
    #pragma unroll
    for (int r=0;r<8;r++) encA[(r0+r)*224 + g] = acc[r] + bias;
  }
}

// ---------------- decoder pipeline (flags, grid=281) ----------------
struct DecArgs{
  const float* Xd; const float* henc; const float* encA;
  const float* h0; const float* c0;
  const float* Whd; const float* Wda; const float* Wca; const float* vat;
  const float* W1; const float* b1; const float* W2; const float* b2;
  const float* Wcs; const float* bcs; const float* Wds; const float* es;
  const int* in_ids; const int* tgt;
  float* hdAll; float* uAll; float* hWdsAll; float* ctxWAll; float* copyAll;
  float* zidxAll; float* partAll; float* clAll; float* nllWg; float* out;
  unsigned* flg;
};

__global__ void __launch_bounds__(256,2) dec_scan(DecArgs A){
  extern __shared__ float sm[];
  float* Wl  = sm;           // 6272
  float* scr = sm + 6272;    // 6400
  const int wg = blockIdx.x, tid = threadIdx.x;
  const int bp = tid & 31, jl = tid >> 5;
  unsigned* fLstmP = A.flg + fLstm;
  unsigned* fP2P   = A.flg + fP2;
  unsigned* fP3P   = A.flg + fP3;
  unsigned* fFinP  = A.flg + fFin;

  if (wg >= 32 && wg < 256){
    // ---------------- P3: vocab sum-exp; W2 row pinned in registers ----------------
    const int wgv = wg - 32;
    const int vs = (wgv*49998)/224, ve = ((wgv+1)*49998)/224;
    const int v = vs + tid;
    const bool valid = v < ve;
    const int vc = valid ? v : 0;
    float4 w2r[14];
    {
      const float4* wr = (const float4*)(A.W2 + (size_t)vc*56);
      #pragma unroll
      for (int q=0;q<14;++q) w2r[q] = wr[q];
    }
    const float b2v = A.b2[vc];
    float* ulL = scr;                  // 1792
    float* redW = scr + 1792;          // 128
    int*   idxL = (int*)(scr + 1920);  // 32
    const int lane = tid & 63, wv2 = tid >> 6;
    for (int s = 0; s < 100; ++s){
      int nt3 = (tid < 32) ? A.tgt[tid*100 + s] : 0;
      wait_slots<false>(fP2P + s*32, 32, tid);
      for (int i = tid; i < 1792; i += 256) ulL[i] = aload(&A.uAll[(size_t)s*1792 + i]);
      if (tid < 32){
        int ix = nt3 - 2; ix = ix<0?0:(ix>49997?49997:ix);
        idxL[tid] = ix;
      }
      __syncthreads();
      #pragma unroll 4
      for (int bb=0; bb<32; ++bb){
        const float4* uv = (const float4*)(ulL + bb*56);
        float z = b2v;
        #pragma unroll
        for (int q=0;q<14;++q){
          float4 u4 = uv[q];
          z += w2r[q].x*u4.x + w2r[q].y*u4.y + w2r[q].z*u4.z + w2r[q].w*u4.w;
        }
        if (valid && v == idxL[bb]) A.zidxAll[s*32+bb] = z;
        float sv2 = valid ? __expf(z) : 0.f;
        #pragma unroll
        for (int o=32;o;o>>=1) sv2 += __shfl_down(sv2,o);
        if (lane == 0) redW[wv2*32+bb] = sv2;
      }
      __syncthreads();
      if (tid < 32){
        float tot = redW[tid]+redW[32+tid]+redW[64+tid]+redW[96+tid];
        A.partAll[(size_t)(s*32+tid)*224 + wgv] = tot;
      }
      __syncthreads();
    }
    __syncthreads();
    if (tid == 0) set_slot(fP3P + wgv);
    // ---------------- finalize stage 1 ----------------
    wait_slots<true>(fP3P, 224, tid);
    float* red = scr + 2048;
    float nll1 = 0.f;
    for (int p = wgv; p < 3200; p += 224){
      float pv = (tid < 224) ? A.partAll[(size_t)p*224 + tid] : 0.f;
      float se = block_sum(pv, red);
      if (tid == 0){
        int s = p >> 5, b = p & 31;
        int nt2 = A.tgt[b*100 + s];
        float xg = A.ctxWAll[p] + A.bcs[0] + A.hWdsAll[p] + A.es[p];
        float pg = 1.f/(1.f + __expf(-xg));
        float genp = (nt2 >= 2 && nt2 < 50000) ? (__expf(A.zidxAll[p]) / se) : 0.f;
        float pr = pg*genp + (1.f-pg)*A.copyAll[p];
        nll1 += -logf(pr + 1e-9f);
      }
    }
    if (tid == 0) A.nllWg[wgv] = nll1;
    __syncthreads();
    if (tid == 0) set_slot(fFinP + wgv);
    // ---------------- finalize stage 2 (one WG) ----------------
    if (wg == 32){
      wait_slots<true>(fFinP, 224, tid);
      float nv = (tid < 224) ? A.nllWg[tid] : 0.f;
      float nll = block_sum(nv, red);
      float cv = (tid < 32) ? A.clAll[tid] : 0.f;
      float cl = block_sum(cv, red);
      if (tid == 0){ A.out[0]=nll; A.out[1]=cl; A.out[2]=nll + 0.75f*cl; }
    }
    return;
  }

  if (wg >= 256){
    // ---------------- decoder LSTM producer (25 WGs) ----------------
    const int wl = wg - 256;
    const int j = wl*8 + jl;
    for (int i = tid; i < 32*196; i += 256){
      int row = i/196, k = i - row*196;
      int gate = row >> 3, jj = row & 7;
      int jg = wl*8 + jj;
      Wl[i] = (jg < 196) ? A.Whd[((size_t)(gate*196 + jg))*196 + k] : 0.f;
    }
    float c = (j < 196) ? A.c0[bp*196 + j] : 0.f;
    const float4* w0 = (const float4*)(Wl + (0*8+jl)*196);
    const float4* w1 = (const float4*)(Wl + (1*8+jl)*196);
    const float4* w2 = (const float4*)(Wl + (2*8+jl)*196);
    const float4* w3 = (const float4*)(Wl + (3*8+jl)*196);
    __syncthreads();
    for (int s = 0; s < 100; ++s){
      float g0=0.f,g1=0.f,g2=0.f,g3=0.f;
      if (j < 196){
        const float* xr = A.Xd + ((size_t)s*32 + bp)*784 + j;
        g0 = xr[0]; g1 = xr[196]; g2 = xr[392]; g3 = xr[588];
      }
      if (s == 0){
        for (int i = tid; i < 6272; i += 256){
          int bb = i/196, k = i - bb*196;
          scr[bb*200 + k] = A.h0[i];
        }
      } else {
        wait_slots<false>(fLstmP + (s-1)*32, 25, tid);
        const float* hp = A.hdAll + (size_t)(s-1)*6272;
        for (int i = tid; i < 6272; i += 256){
          int bb = i/196, k = i - bb*196;
          scr[bb*200 + k] = aload(&hp[i]);
        }
      }
      __syncthreads();
      if (j < 196){
        const float4* hr = (const float4*)(scr + bp*200);
        #pragma unroll 7
        for (int q = 0; q < 49; ++q){
          float4 hv = hr[q];
          float4 a0 = w0[q], a1 = w1[q], a2 = w2[q], a3 = w3[q];
          g0 += hv.x*a0.x + hv.y*a0.y + hv.z*a0.z + hv.w*a0.w;
          g1 += hv.x*a1.x + hv.y*a1.y + hv.z*a1.z + hv.w*a1.w;
          g2 += hv.x*a2.x + hv.y*a2.y + hv.z*a2.z + hv.w*a2.w;
          g3 += hv.x*a3.x + hv.y*a3.y + hv.z*a3.z + hv.w*a3.w;
        }
        float ig = sigm(g0), fg = sigm(g1), gc = fast_tanh(g2), og = sigm(g3);
        c = fg*c + ig*gc;
        float h = og * fast_tanh(c);
        A.hdAll[(size_t)s*6272 + bp*196 + j] = h;
      }
      __syncthreads();
      if (tid == 0) set_slot(fLstmP + s*32 + wl);
    }
    return;
  }

  // ---------------- P2: attention + ctx + u (32 WGs, b = wg) ----------------
  const int b = wg;
  float* wcaL = Wl; float* vL = Wl+224; float* WcsL = Wl+448;
  float* b1L = Wl+768; float* WdsL = Wl+824;
  if (tid < 224){ wcaL[tid] = A.Wca[tid]; vL[tid] = A.vat[tid]; }
  for (int i = tid; i < 320; i += 256) WcsL[i] = A.Wcs[i];
  if (tid < 56) b1L[tid] = A.b1[tid];
  if (tid < 196) WdsL[tid] = A.Wds[tid];
  const int inid = A.in_ids[b*256 + tid];
  const float4* erow = (const float4*)(A.encA + (size_t)(b*256+tid)*224);
  float cov = 0.f, clr = 0.f;
  float* hl2   = scr;          // 200
  float* hwda  = scr + 200;    // 224
  float* attnL = scr + 424;    // 256
  float* pctx  = scr + 680;    // 3*80*4 = 960
  float* ctxL  = scr + 1640;   // 320
  float* red   = scr + 1960;   // 4
  __syncthreads();
  for (int s = 0; s < 100; ++s){
    wait_slots<false>(fLstmP + s*32, 25, tid);
    if (tid < 196) hl2[tid] = aload(&A.hdAll[(size_t)s*6272 + b*196 + tid]);
    __syncthreads();
    if (tid < 224){
      const float* wr = A.Wda + (size_t)tid*196;
      float acc = 0.f;
      #pragma unroll 4
      for (int q = 0; q < 196; ++q) acc += hl2[q]*wr[q];
      hwda[tid] = acc;
    } else {
      int l = tid - 224; float acc = 0.f;
      for (int q = l; q < 196; q += 32) acc += hl2[q]*WdsL[q];
      #pragma unroll
      for (int o=16;o;o>>=1) acc += __shfl_down(acc,o,32);
      if (l==0) A.hWdsAll[s*32 + b] = acc;
    }
    __syncthreads();
    float exv = 0.f;
    if (inid != 0){
      float acc = 0.f;
      #pragma unroll 8
      for (int q = 0; q < 56; ++q){
        float4 ev = erow[q]; int a0 = 4*q;
        acc += fast_tanh(ev.x + hwda[a0]   + cov*wcaL[a0]  )*vL[a0];
        acc += fast_tanh(ev.y + hwda[a0+1] + cov*wcaL[a0+1])*vL[a0+1];
        acc += fast_tanh(ev.z + hwda[a0+2] + cov*wcaL[a0+2])*vL[a0+2];
        acc += fast_tanh(ev.w + hwda[a0+3] + cov*wcaL[a0+3])*vL[a0+3];
      }
      exv = __expf(acc);
    }
    float S = block_sum(exv, red);
    float attn = exv * __builtin_amdgcn_rcpf(S);
    attnL[tid] = attn;
    const int ntb = A.tgt[b*100 + s];
    float cpS = block_sum((inid == ntb) ? attn : 0.f, red);
    float mnS = block_sum(fminf(attn, cov), red);
    if (tid == 0){
      A.copyAll[s*32 + b] = cpS;
      clr += mnS;
      if (s == 99) A.clAll[b] = clr;
    }
    cov += attn;
    if (tid < 240){
      int seg = tid/80, h4 = tid - seg*80;
      int t0 = seg*86, t1 = (t0+86 < 256) ? t0+86 : 256;
      const float* base = (h4 < 40)
        ? (A.henc + (size_t)b*160 + (size_t)h4*4)
        : (A.henc + (size_t)256*5120 + (size_t)b*160 + (size_t)(h4-40)*4);
      float4 accv = {0.f,0.f,0.f,0.f};
      #pragma unroll 4
      for (int t2 = t0; t2 < t1; ++t2){
        float a = attnL[t2];
        float4 ev = *(const float4*)(base + (size_t)t2*5120);
        accv.x += a*ev.x; accv.y += a*ev.y; accv.z += a*ev.z; accv.w += a*ev.w;
      }
      *(float4*)(pctx + (seg*80+h4)*4) = accv;
    }
    __syncthreads();
    if (tid < 80){
      float4 p0 = *(float4*)(pctx + tid*4);
      float4 p1 = *(float4*)(pctx + (80+tid)*4);
      float4 p2v = *(float4*)(pctx + (160+tid)*4);
      float4 cvv;
      cvv.x = p0.x+p1.x+p2v.x; cvv.y = p0.y+p1.y+p2v.y;
      cvv.z = p0.z+p1.z+p2v.z; cvv.w = p0.w+p1.w+p2v.w;
      *(float4*)(ctxL + tid*4) = cvv;
    }
    __syncthreads();
    if (tid < 224){
      int g = tid >> 2, ks = tid & 3;
      const float* wr = A.W1 + (size_t)g*516;
      float acc = 0.f;
      #pragma unroll 4
      for (int q = ks; q < 516; q += 4){
        float hv = (q < 196) ? hl2[q] : ctxL[q-196];
        acc += hv*wr[q];
      }
      acc += __shfl_down(acc,2,4); acc += __shfl_down(acc,1,4);
      if (ks == 0) A.uAll[(size_t)s*1792 + b*56 + g] = fast_tanh(acc + b1L[g]);
    } else {
      int l = tid - 224; float acc = 0.f;
      for (int q = l; q < 320; q += 32) acc += ctxL[q]*WcsL[q];
      #pragma unroll
      for (int o=16;o;o>>=1) acc += __shfl_down(acc,o,32);
      if (l==0) A.ctxWAll[s*32 + b] = acc;
    }
    __syncthreads();
    if (tid == 0) set_slot(fP2P + s*32 + b);
  }
}

// ---------------- host launch ----------------
extern "C" void kernel_launch(void* const* d_in, const int* in_sizes, int n_in,
                              void* d_out, int out_size, void* d_ws, size_t ws_size,
                              hipStream_t stream){
  const int*   in_ids = (const int*)  d_in[0];
  const int*   tgt    = (const int*)  d_in[1];
  const float* emb    = (const float*)d_in[3];
  const float* Wi_f   = (const float*)d_in[4];
  const float* Wh_f   = (const float*)d_in[5];
  const float* bi_f   = (const float*)d_in[6];
  const float* bh_f   = (const float*)d_in[7];
  const float* Wi_b   = (const float*)d_in[8];
  const float* Wh_b   = (const float*)d_in[9];
  const float* bi_b   = (const float*)d_in[10];
  const float* bh_b   = (const float*)d_in[11];
  const float* Weh    = (const float*)d_in[12];
  const float* beh    = (const float*)d_in[13];
  const float* Wec    = (const float*)d_in[14];
  const float* bec    = (const float*)d_in[15];
  const float* Wi_d   = (const float*)d_in[16];
  const float* Wh_d   = (const float*)d_in[17];
  const float* bi_d   = (const float*)d_in[18];
  const float* bh_d   = (const float*)d_in[19];
  const float* Wea    = (const float*)d_in[20];
  const float* bea    = (const float*)d_in[21];
  const float* Wda    = (const float*)d_in[22];
  const float* Wca    = (const float*)d_in[23];
  const float* vat    = (const float*)d_in[24];
  const float* W1     = (const float*)d_in[25];
  const float* b1     = (const float*)d_in[26];
  const float* W2     = (const float*)d_in[27];
  const float* b2     = (const float*)d_in[28];
  const float* Wcs    = (const float*)d_in[29];
  const float* bcs    = (const float*)d_in[30];
  const float* Wds    = (const float*)d_in[31];
  const float* Wes    = (const float*)d_in[32];

  float* ws = (float*)d_ws;
  int* iBase = (int*)(ws + oFEnd);
  int* in_mapped = iBase;
  int* cur_ids   = iBase + 8192;
  unsigned* flags = (unsigned*)(iBase + 11392);

  prep_kernel<<<128, 256, 0, stream>>>(in_ids, tgt, in_mapped, cur_ids, flags);

  { RGArgs a{nullptr, in_mapped, emb, Wi_f, bi_f, bh_f, ws + oXf, 128, 640};
    rowgemm<<<1024, 256, 8*128*4, stream>>>(a); }
  { RGArgs a{nullptr, in_mapped, emb, Wi_b, bi_b, bh_b, ws + oXb, 128, 640};
    rowgemm<<<1024, 256, 8*128*4, stream>>>(a); }
  { RGArgs a{nullptr, cur_ids, emb, Wi_d, bi_d, bh_d, ws + oXd, 128, 784};
    rowgemm<<<400, 256, 8*128*4, stream>>>(a); }

  es_kernel<<<3200, 64, 0, stream>>>(cur_ids, emb, Wes, ws + oEs);

  { EncArgs ea{ws + oXf, ws + oXb, Wh_f, Wh_b, ws + oHenc, ws + oCT, flags + fEnc};
    void* ka[] = {&ea};
    hipLaunchCooperativeKernel((void*)enc_scan, dim3(40), dim3(256), ka,
                               (unsigned)((5120 + 32*164)*4), stream); }

  mid_kernel<<<32, 256, 0, stream>>>(ws + oHenc, ws + oCT, Weh, beh, Wec, bec,
                                     ws + oH0, ws + oC0);

  encA_gemm<<<1024, 256, 0, stream>>>(ws + oHenc, Wea, bea, ws + oEncA);

  { DecArgs da{ws + oXd, ws + oHenc, ws + oEncA,
               ws + oH0, ws + oC0,
               Wh_d, Wda, Wca, vat,
               W1, b1, W2, b2, Wcs, bcs, Wds, ws + oEs,
               in_ids, tgt,
               ws + oHdAll, ws + oUAll, ws + oHWdsAll, ws + oCtxWAll, ws + oCopyAll,
               ws + oZidxAll, ws + oPartAll, ws + oClAll, ws + oNllWg, (float*)d_out,
               flags};
    void* ka[] = {&da};
    hipLaunchCooperativeKernel((void*)dec_scan, dim3(281), dim3(256), ka,
                               (unsigned)((6272 + 6400)*4), stream); }
}

// Round 4
// 5865.012 us; speedup vs baseline: 3.3838x; 1.0034x over previous
//
#include <hip/hip_runtime.h>

#define MSCOPE __HIP_MEMORY_SCOPE_AGENT

// ---------------- model dims ----------------
// V=50000 E=128 H=160 D=196 A=224 BN=56, B=32, Tin=256, Ttgt=100
// encoder gates 4H=640, decoder gates 4D=784, 2H=320, D+2H=516, V-END=49998
// X layouts are TRANSPOSED: Xf/Xb = [t][640][32], Xd = [s][784][32]

// ---------------- ws float layout ----------------
constexpr size_t oXf   = 0;                                // 256 x 640 x 32
constexpr size_t oXb   = oXf   + (size_t)8192*640;
constexpr size_t oXd   = oXb   + (size_t)8192*640;         // 100 x 784 x 32
constexpr size_t oHenc = oXd   + (size_t)3200*784;         // 2 x 256 x (32*160)
constexpr size_t oEncA = oHenc + (size_t)2*256*5120;       // 8192 x 224
constexpr size_t oEs   = oEncA + (size_t)8192*224;         // 3200
constexpr size_t oCT   = oEs   + 3200;                     // 2 x 5120
constexpr size_t oH0   = oCT   + 10240;                    // 32 x 196
constexpr size_t oC0   = oH0   + 6272;                     // 32 x 196
constexpr size_t oHWdsAll = oC0 + 6272;                    // 100 x 32
constexpr size_t oCtxWAll = oHWdsAll + 3200;
constexpr size_t oCopyAll = oCtxWAll + 3200;
constexpr size_t oZidxAll = oCopyAll + 3200;
constexpr size_t oClAll   = oZidxAll + 3200;               // 32
constexpr size_t oNllWg   = oClAll + 32;                   // 224
constexpr size_t oFEnd    = oNllWg + 224;
// dec-phase overlays on the (dead) Xf region:
constexpr size_t oHdAll   = 0;                             // 100 x 32 x 196
constexpr size_t oUAll    = oHdAll + (size_t)100*6272;     // 100 x 32 x 56
constexpr size_t oPartAll = oUAll  + (size_t)100*1792;     // 100 x 32 x 224
// ints after floats: in_mapped[8192], cur_ids[3200], flags[23232]
constexpr int fEnc  = 0;          // 2*256*32
constexpr int fLstm = 16384;      // 100*32
constexpr int fP2   = 19584;      // 100*32
constexpr int fP3   = 22784;      // 224
constexpr int fFin  = 23008;      // 224
constexpr int fEnd  = 23232;

// ---------------- helpers ----------------
__device__ __forceinline__ float fast_tanh(float x){
  float e = __expf(-2.f*fabsf(x));
  float r = (1.f - e) * __builtin_amdgcn_rcpf(1.f + e);
  return copysignf(r, x);
}
__device__ __forceinline__ float sigm(float x){
  return __builtin_amdgcn_rcpf(1.f + __expf(-x));
}
// relaxed agent-scope ops: write-through/read-from LLC, NO buffer_wbl2/buffer_inv
__device__ __forceinline__ float aload(const float* p){
  return __hip_atomic_load(const_cast<float*>(p), __ATOMIC_RELAXED, MSCOPE);
}
__device__ __forceinline__ float2 aload2(const float* p){
  unsigned long long u = __hip_atomic_load(
      reinterpret_cast<unsigned long long*>(const_cast<float*>(p)),
      __ATOMIC_RELAXED, MSCOPE);
  float2 r; __builtin_memcpy(&r, &u, 8); return r;
}
__device__ __forceinline__ void astore(float* p, float v){
  __hip_atomic_store(p, v, __ATOMIC_RELAXED, MSCOPE);
}
__device__ __forceinline__ void wait_slots(unsigned* slots, int n, int tid){
  if (tid < 64){
    for(;;){
      bool miss = false;
      for (int i = tid; i < n; i += 64)
        if (__hip_atomic_load(&slots[i], __ATOMIC_RELAXED, MSCOPE) == 0u) miss = true;
      if (__ballot(miss) == 0ULL) break;
      __builtin_amdgcn_s_sleep(1);
    }
  }
  __syncthreads();
}
// NOTE: callers must __syncthreads() (drains vmcnt -> prior atomic stores are
// at LLC) before set_slot. Flag itself is relaxed: manual release w/o wbl2.
__device__ __forceinline__ void set_slot(unsigned* slot){
  __hip_atomic_store(slot, 1u, __ATOMIC_RELAXED, MSCOPE);
}
__device__ __forceinline__ float block_sum(float v, float* red){
  #pragma unroll
  for (int o=32;o;o>>=1) v += __shfl_down(v,o);
  if ((threadIdx.x&63)==0) red[threadIdx.x>>6] = v;
  __syncthreads();
  v = red[0]+red[1]+red[2]+red[3];
  __syncthreads();
  return v;
}

// ---------------- prep: id mapping + flag zeroing ----------------
__global__ void prep_kernel(const int* __restrict__ in_ids, const int* __restrict__ tgt,
                            int* __restrict__ in_mapped, int* __restrict__ cur_ids,
                            unsigned* __restrict__ flags){
  int i = blockIdx.x*256 + threadIdx.x;
  if (i < 8192){
    int t = i >> 5, b = i & 31;
    int id = in_ids[b*256 + t];
    in_mapped[i] = (id >= 50000) ? 3 : id;
  }
  if (i < 3200){
    int k = i >> 5, b = i & 31;
    int id = (k == 0) ? 1 : tgt[b*100 + (k-1)];
    cur_ids[i] = (id >= 50000) ? 3 : id;
  }
  if (i < fEnd) flags[i] = 0u;
}

// ------- rowgemm_t: one block per timestep t; out[(t*N+g)*32 + b] -------
struct RGTArgs{ const int* gid; const float* emb; const float* W;
                const float* bias1; const float* bias2; float* out; int N; };
__global__ void __launch_bounds__(256) rowgemm_t(RGTArgs a){
  __shared__ float xl[32*128];
  const int tid = threadIdx.x;
  const int t = blockIdx.x;
  const int N = a.N;
  for (int i = tid; i < 32*128; i += 256){
    int r = i >> 7, k = i & 127;
    xl[i] = a.emb[(size_t)a.gid[t*32 + r]*128 + k];
  }
  __syncthreads();
  for (int g = tid; g < N; g += 256){
    const float* wr = a.W + (size_t)g*128;
    float bias = a.bias1[g] + a.bias2[g];
    float acc[32];
    #pragma unroll
    for (int r=0;r<32;r++) acc[r]=bias;
    for (int k=0;k<128;k+=4){
      float4 wv = *(const float4*)(wr+k);
      #pragma unroll
      for (int r=0;r<32;r++){
        float4 xv = *(const float4*)(xl + r*128 + k);
        acc[r] += wv.x*xv.x + wv.y*xv.y + wv.z*xv.z + wv.w*xv.w;
      }
    }
    float* op = a.out + ((size_t)t*N + g)*32;
    #pragma unroll
    for (int r=0;r<32;r+=4)
      *(float4*)(op+r) = make_float4(acc[r],acc[r+1],acc[r+2],acc[r+3]);
  }
}

// ---------------- row GEMM (src path, for encA) ----------------
struct RGArgs{ const float* src; const float* W;
               const float* bias1; float* out; int K; int N; };
__global__ void __launch_bounds__(256) rowgemm(RGArgs a){
  extern __shared__ float rl[];   // 8 x K
  const int tid = threadIdx.x;
  const int K = a.K, N = a.N;
  const size_t r0 = (size_t)blockIdx.x*8;
  for (int i = tid; i < 8*K; i += 256){
    int r = i / K, k = i - r*K;
    rl[i] = a.src[(r0+r)*(size_t)K + k];
  }
  __syncthreads();
  for (int g = tid; g < N; g += 256){
    const float* wr = a.W + (size_t)g*K;
    float acc[8];
    #pragma unroll
    for (int r=0;r<8;r++) acc[r]=0.f;
    for (int k=0;k<K;k+=4){
      float4 wv = *(const float4*)(wr+k);
      #pragma unroll
      for (int r=0;r<8;r++){
        float4 xv = *(const float4*)(rl + r*K + k);
        acc[r] += wv.x*xv.x + wv.y*xv.y + wv.z*xv.z + wv.w*xv.w;
      }
    }
    float bias = a.bias1[g];
    #pragma unroll
    for (int r=0;r<8;r++) a.out[(r0+r)*(size_t)N + g] = acc[r] + bias;
  }
}

// ---------------- es[r] = emb[gid[r]] . Wes ----------------
__global__ void es_kernel(const int* __restrict__ gid, const float* __restrict__ emb,
                          const float* __restrict__ Wes, float* __restrict__ es){
  int r = blockIdx.x, l = threadIdx.x;
  const float* e = emb + (size_t)gid[r]*128;
  float acc = e[l]*Wes[l] + e[l+64]*Wes[l+64];
  #pragma unroll
  for (int o=32;o;o>>=1) acc += __shfl_down(acc,o);
  if (l==0) es[r] = acc;
}

// ---------------- encoder bidirectional LSTM scan (flags, grid=40) ----------------
struct EncArgs{ const float* Xf; const float* Xb; const float* Whf; const float* Whb;
                float* henc; float* cT; unsigned* done; };
__global__ void __launch_bounds__(256) enc_scan(EncArgs a){
  extern __shared__ float sm[];
  float* Wl = sm;           // 5120
  float* hl = sm + 5120;    // 32 x 164
  const int wg = blockIdx.x;
  const int dir = wg/20, jwg = wg%20;
  const int tid = threadIdx.x;
  const int b = tid & 31, jl = tid >> 5;
  const int j = jwg*8 + jl;
  const float* Wh = dir ? a.Whb : a.Whf;
  const float* X  = dir ? a.Xb  : a.Xf;
  float* H = a.henc + (size_t)dir*256*5120;
  unsigned* done = a.done + dir*256*32;
  for (int i = tid; i < 32*160; i += 256){
    int row = i/160, k = i - row*160;
    int gate = row >> 3, jj = row & 7;
    Wl[i] = Wh[((size_t)(gate*160 + jwg*8 + jj))*160 + k];
  }
  float c = 0.f;
  const float4* w0 = (const float4*)(Wl + (0*8+jl)*160);
  const float4* w1 = (const float4*)(Wl + (1*8+jl)*160);
  const float4* w2 = (const float4*)(Wl + (2*8+jl)*160);
  const float4* w3 = (const float4*)(Wl + (3*8+jl)*160);
  __syncthreads();
  for (int t = 0; t < 256; ++t){
    const int trow = dir ? (255 - t) : t;
    // X loads issue before the flag wait (hide HBM latency); layout [t][g*160+j][b]
    const float* xr = X + ((size_t)trow*640 + j)*32 + b;
    float g0 = xr[0], g1 = xr[5120], g2 = xr[10240], g3 = xr[15360];
    if (t > 0){
      wait_slots(done + (t-1)*32, 20, tid);
      const int tprev = dir ? (256 - t) : (t-1);
      const float* hp = H + (size_t)tprev*5120;
      for (int i2 = tid; i2 < 2560; i2 += 256){
        float2 v = aload2(hp + i2*2);
        int bb = i2/80, kk = (i2 - bb*80)*2;
        *(float2*)(hl + bb*164 + kk) = v;
      }
    } else {
      for (int i = tid; i < 5120; i += 256){ int bb=i/160,k=i-bb*160; hl[bb*164+k]=0.f; }
    }
    __syncthreads();
    const float4* hr = (const float4*)(hl + b*164);
    #pragma unroll 4
    for (int q = 0; q < 40; ++q){
      float4 hv = hr[q];
      float4 a0 = w0[q], a1 = w1[q], a2 = w2[q], a3 = w3[q];
      g0 += hv.x*a0.x + hv.y*a0.y + hv.z*a0.z + hv.w*a0.w;
      g1 += hv.x*a1.x + hv.y*a1.y + hv.z*a1.z + hv.w*a1.w;
      g2 += hv.x*a2.x + hv.y*a2.y + hv.z*a2.z + hv.w*a2.w;
      g3 += hv.x*a3.x + hv.y*a3.y + hv.z*a3.z + hv.w*a3.w;
    }
    float ig = sigm(g0), fg = sigm(g1), gc = fast_tanh(g2), og = fast_tanh(c = fg*c + ig*gc) * sigm(g3);
    float h = og;
    astore(&H[(size_t)trow*5120 + b*160 + j], h);
    __syncthreads();                       // drains vmcnt: h stores visible at LLC
    if (tid == 0) set_slot(done + t*32 + jwg);
  }
  a.cT[dir*5120 + b*160 + j] = c;
}

// ---------------- mid: h0/c0 projections ----------------
__global__ void mid_kernel(const float* __restrict__ henc, const float* __restrict__ cT,
                           const float* __restrict__ Weh, const float* __restrict__ beh,
                           const float* __restrict__ Wec, const float* __restrict__ bec,
                           float* __restrict__ h0, float* __restrict__ c0){
  __shared__ float hc[320], cc[320];
  int b = blockIdx.x, tid = threadIdx.x;
  if (tid < 160){
    hc[tid]     = henc[(size_t)255*5120 + b*160 + tid];        // fwd final
    hc[160+tid] = henc[(size_t)256*5120 + b*160 + tid];        // bwd final (t_orig=0)
    cc[tid]     = cT[b*160 + tid];
    cc[160+tid] = cT[5120 + b*160 + tid];
  }
  __syncthreads();
  for (int g = tid; g < 196; g += 256){
    const float* w1 = Weh + (size_t)g*320;
    const float* w2 = Wec + (size_t)g*320;
    float a1 = beh[g], a2 = bec[g];
    for (int k = 0; k < 320; ++k){ a1 += hc[k]*w1[k]; a2 += cc[k]*w2[k]; }
    h0[b*196 + g] = a1;
    c0[b*196 + g] = a2;
  }
}

// ---------------- encA = [hf;hb] @ Wea.T + bea ----------------
__global__ void __launch_bounds__(256) encA_gemm(const float* __restrict__ henc,
                 const float* __restrict__ Wea, const float* __restrict__ bea,
                 float* __restrict__ encA){
  __shared__ float rl[8*320];
  const int tid = threadIdx.x;
  const size_t r0 = (size_t)blockIdx.x*8;
  for (int i = tid; i < 8*320; i += 256){
    int r = i/320, k = i - r*320;
    size_t row = r0 + r; int b = (int)(row >> 8), t = (int)(row & 255);
    rl[i] = (k < 160) ? henc[(size_t)t*5120 + b*160 + k]
                      : henc[(size_t)(256+t)*5120 + b*160 + (k-160)];
  }
  __syncthreads();
  for (int g = tid; g < 224; g += 256){
    const float* wr = Wea + (size_t)g*320;
    float acc[8];
    #pragma unroll
    for (int r=0;r<8;r++) acc[r]=0.f;
    for (int k=0;k<320;k+=4){
      float4 wv = *(const float4*)(wr+k);
      #pragma unroll
      for (int r=0;r<8;r++){
        float4 xv = *(const float4*)(rl + r*320 + k);
        acc[r] += wv.x*xv.x + wv.y*xv.y + wv.z*xv.z + wv.w*xv.w;
      }
    }
    float bias = bea[g];
    #pragma unroll
    for (int r=0;r<8;r++) encA[(r0+r)*224 + g] = acc[r] + bias;
  }
}

// ---------------- decoder pipeline (flags, grid=281) ----------------
struct DecArgs{
  const float* Xd; const float* henc; const float* encA;
  const float* h0; const float* c0;
  const float* Whd; const float* Wda; const float* Wca; const float* vat;
  const float* W1; const float* b1; const float* W2; const float* b2;
  const float* Wcs; const float* bcs; const float* Wds; const float* es;
  const int* in_ids; const int* tgt;
  float* hdAll; float* uAll; float* hWdsAll; float* ctxWAll; float* copyAll;
  float* zidxAll; float* partAll; float* clAll; float* nllWg; float* out;
  unsigned* flg;
};

__global__ void __launch_bounds__(256,2) dec_scan(DecArgs A){
  extern __shared__ float sm[];
  float* Wl  = sm;           // 6272
  float* scr = sm + 6272;    // 6400
  const int wg = blockIdx.x, tid = threadIdx.x;
  const int bp = tid & 31, jl = tid >> 5;
  unsigned* fLstmP = A.flg + fLstm;
  unsigned* fP2P   = A.flg + fP2;
  unsigned* fP3P   = A.flg + fP3;
  unsigned* fFinP  = A.flg + fFin;

  if (wg >= 32 && wg < 256){
    // ---------------- P3: vocab sum-exp; W2 row pinned in registers ----------------
    const int wgv = wg - 32;
    const int vs = (wgv*49998)/224, ve = ((wgv+1)*49998)/224;
    const int v = vs + tid;
    const bool valid = v < ve;
    const int vc = valid ? v : 0;
    float4 w2r[14];
    {
      const float4* wr = (const float4*)(A.W2 + (size_t)vc*56);
      #pragma unroll
      for (int q=0;q<14;++q) w2r[q] = wr[q];
    }
    const float b2v = A.b2[vc];
    float* ulL = scr;                  // 1792
    float* redW = scr + 1792;          // 128
    int*   idxL = (int*)(scr + 1920);  // 32
    const int lane = tid & 63, wv2 = tid >> 6;
    for (int s = 0; s < 100; ++s){
      int nt3 = (tid < 32) ? A.tgt[tid*100 + s] : 0;
      wait_slots(fP2P + s*32, 32, tid);
      for (int i2 = tid; i2 < 896; i2 += 256){
        float2 u2 = aload2(&A.uAll[(size_t)s*1792 + i2*2]);
        *(float2*)(ulL + i2*2) = u2;
      }
      if (tid < 32){
        int ix = nt3 - 2; ix = ix<0?0:(ix>49997?49997:ix);
        idxL[tid] = ix;
      }
      __syncthreads();
      #pragma unroll 4
      for (int bb=0; bb<32; ++bb){
        const float4* uv = (const float4*)(ulL + bb*56);
        float z = b2v;
        #pragma unroll
        for (int q=0;q<14;++q){
          float4 u4 = uv[q];
          z += w2r[q].x*u4.x + w2r[q].y*u4.y + w2r[q].z*u4.z + w2r[q].w*u4.w;
        }
        if (valid && v == idxL[bb]) astore(&A.zidxAll[s*32+bb], z);
        float sv2 = valid ? __expf(z) : 0.f;
        #pragma unroll
        for (int o=32;o;o>>=1) sv2 += __shfl_down(sv2,o);
        if (lane == 0) redW[wv2*32+bb] = sv2;
      }
      __syncthreads();
      if (tid < 32){
        float tot = redW[tid]+redW[32+tid]+redW[64+tid]+redW[96+tid];
        astore(&A.partAll[(size_t)(s*32+tid)*224 + wgv], tot);
      }
      __syncthreads();
    }
    __syncthreads();
    if (tid == 0) set_slot(fP3P + wgv);
    // ---------------- finalize stage 1 ----------------
    wait_slots(fP3P, 224, tid);
    float* red = scr + 2048;
    float nll1 = 0.f;
    for (int p = wgv; p < 3200; p += 224){
      float pv = (tid < 224) ? aload(&A.partAll[(size_t)p*224 + tid]) : 0.f;
      float se = block_sum(pv, red);
      if (tid == 0){
        int s = p >> 5, b = p & 31;
        int nt2 = A.tgt[b*100 + s];
        float xg = aload(&A.ctxWAll[p]) + A.bcs[0] + aload(&A.hWdsAll[p]) + A.es[p];
        float pg = 1.f/(1.f + __expf(-xg));
        float genp = (nt2 >= 2 && nt2 < 50000) ? (__expf(aload(&A.zidxAll[p])) / se) : 0.f;
        float pr = pg*genp + (1.f-pg)*aload(&A.copyAll[p]);
        nll1 += -logf(pr + 1e-9f);
      }
    }
    if (tid == 0) astore(&A.nllWg[wgv], nll1);
    __syncthreads();
    if (tid == 0) set_slot(fFinP + wgv);
    // ---------------- finalize stage 2 (one WG) ----------------
    if (wg == 32){
      wait_slots(fFinP, 224, tid);
      float nv = (tid < 224) ? aload(&A.nllWg[tid]) : 0.f;
      float nll = block_sum(nv, red);
      float cv = (tid < 32) ? aload(&A.clAll[tid]) : 0.f;
      float cl = block_sum(cv, red);
      if (tid == 0){ A.out[0]=nll; A.out[1]=cl; A.out[2]=nll + 0.75f*cl; }
    }
    return;
  }

  if (wg >= 256){
    // ---------------- decoder LSTM producer (25 WGs) ----------------
    const int wl = wg - 256;
    const int j = wl*8 + jl;
    for (int i = tid; i < 32*196; i += 256){
      int row = i/196, k = i - row*196;
      int gate = row >> 3, jj = row & 7;
      int jg = wl*8 + jj;
      Wl[i] = (jg < 196) ? A.Whd[((size_t)(gate*196 + jg))*196 + k] : 0.f;
    }
    float c = (j < 196) ? A.c0[bp*196 + j] : 0.f;
    const float4* w0 = (const float4*)(Wl + (0*8+jl)*196);
    const float4* w1 = (const float4*)(Wl + (1*8+jl)*196);
    const float4* w2 = (const float4*)(Wl + (2*8+jl)*196);
    const float4* w3 = (const float4*)(Wl + (3*8+jl)*196);
    __syncthreads();
    for (int s = 0; s < 100; ++s){
      float g0=0.f,g1=0.f,g2=0.f,g3=0.f;
      if (j < 196){
        // Xd layout [s][g*196+j][b]
        const float* xr = A.Xd + ((size_t)s*784 + j)*32 + bp;
        g0 = xr[0]; g1 = xr[6272]; g2 = xr[12544]; g3 = xr[18816];
      }
      if (s == 0){
        for (int i = tid; i < 6272; i += 256){
          int bb = i/196, k = i - bb*196;
          scr[bb*200 + k] = A.h0[i];
        }
      } else {
        wait_slots(fLstmP + (s-1)*32, 25, tid);
        const float* hp = A.hdAll + (size_t)(s-1)*6272;
        for (int i2 = tid; i2 < 3136; i2 += 256){
          float2 hv2 = aload2(hp + i2*2);
          int bb = (i2*2)/196, kk = i2*2 - bb*196;
          *(float2*)(scr + bb*200 + kk) = hv2;
        }
      }
      __syncthreads();
      if (j < 196){
        const float4* hr = (const float4*)(scr + bp*200);
        #pragma unroll 7
        for (int q = 0; q < 49; ++q){
          float4 hv = hr[q];
          float4 a0 = w0[q], a1 = w1[q], a2 = w2[q], a3 = w3[q];
          g0 += hv.x*a0.x + hv.y*a0.y + hv.z*a0.z + hv.w*a0.w;
          g1 += hv.x*a1.x + hv.y*a1.y + hv.z*a1.z + hv.w*a1.w;
          g2 += hv.x*a2.x + hv.y*a2.y + hv.z*a2.z + hv.w*a2.w;
          g3 += hv.x*a3.x + hv.y*a3.y + hv.z*a3.z + hv.w*a3.w;
        }
        float ig = sigm(g0), fg = sigm(g1), gc = fast_tanh(g2), og = sigm(g3);
        c = fg*c + ig*gc;
        float h = og * fast_tanh(c);
        astore(&A.hdAll[(size_t)s*6272 + bp*196 + j], h);
      }
      __syncthreads();               // drains vmcnt
      if (tid == 0) set_slot(fLstmP + s*32 + wl);
    }
    return;
  }

  // ---------------- P2: attention + ctx + u (32 WGs, b = wg) ----------------
  const int b = wg;
  float* wcaL = Wl; float* vL = Wl+224; float* WcsL = Wl+448;
  float* b1L = Wl+768; float* WdsL = Wl+824;
  if (tid < 224){ wcaL[tid] = A.Wca[tid]; vL[tid] = A.vat[tid]; }
  for (int i = tid; i < 320; i += 256) WcsL[i] = A.Wcs[i];
  if (tid < 56) b1L[tid] = A.b1[tid];
  if (tid < 196) WdsL[tid] = A.Wds[tid];
  const int inid = A.in_ids[b*256 + tid];
  const float4* erow = (const float4*)(A.encA + (size_t)(b*256+tid)*224);
  float cov = 0.f, clr = 0.f;
  float* hl2   = scr;          // 200
  float* hwda  = scr + 200;    // 224
  float* attnL = scr + 424;    // 256
  float* pctx  = scr + 680;    // 3*80*4 = 960
  float* ctxL  = scr + 1640;   // 320
  float* red   = scr + 1960;   // 4
  __syncthreads();
  for (int s = 0; s < 100; ++s){
    wait_slots(fLstmP + s*32, 25, tid);
    if (tid < 196) hl2[tid] = aload(&A.hdAll[(size_t)s*6272 + b*196 + tid]);
    __syncthreads();
    if (tid < 224){
      const float* wr = A.Wda + (size_t)tid*196;
      float acc = 0.f;
      #pragma unroll 4
      for (int q = 0; q < 196; ++q) acc += hl2[q]*wr[q];
      hwda[tid] = acc;
    } else {
      int l = tid - 224; float acc = 0.f;
      for (int q = l; q < 196; q += 32) acc += hl2[q]*WdsL[q];
      #pragma unroll
      for (int o=16;o;o>>=1) acc += __shfl_down(acc,o,32);
      if (l==0) astore(&A.hWdsAll[s*32 + b], acc);
    }
    __syncthreads();
    float exv = 0.f;
    if (inid != 0){
      float acc = 0.f;
      #pragma unroll 8
      for (int q = 0; q < 56; ++q){
        float4 ev = erow[q]; int a0 = 4*q;
        acc += fast_tanh(ev.x + hwda[a0]   + cov*wcaL[a0]  )*vL[a0];
        acc += fast_tanh(ev.y + hwda[a0+1] + cov*wcaL[a0+1])*vL[a0+1];
        acc += fast_tanh(ev.z + hwda[a0+2] + cov*wcaL[a0+2])*vL[a0+2];
        acc += fast_tanh(ev.w + hwda[a0+3] + cov*wcaL[a0+3])*vL[a0+3];
      }
      exv = __expf(acc);
    }
    float S = block_sum(exv, red);
    float attn = exv * __builtin_amdgcn_rcpf(S);
    attnL[tid] = attn;
    const int ntb = A.tgt[b*100 + s];
    float cpS = block_sum((inid == ntb) ? attn : 0.f, red);
    float mnS = block_sum(fminf(attn, cov), red);
    if (tid == 0){
      astore(&A.copyAll[s*32 + b], cpS);
      clr += mnS;
      if (s == 99) astore(&A.clAll[b], clr);
    }
    cov += attn;
    if (tid < 240){
      int seg = tid/80, h4 = tid - seg*80;
      int t0 = seg*86, t1 = (t0+86 < 256) ? t0+86 : 256;
      const float* base = (h4 < 40)
        ? (A.henc + (size_t)b*160 + (size_t)h4*4)
        : (A.henc + (size_t)256*5120 + (size_t)b*160 + (size_t)(h4-40)*4);
      float4 accv = {0.f,0.f,0.f,0.f};
      #pragma unroll 4
      for (int t2 = t0; t2 < t1; ++t2){
        float a = attnL[t2];
        float4 ev = *(const float4*)(base + (size_t)t2*5120);
        accv.x += a*ev.x; accv.y += a*ev.y; accv.z += a*ev.z; accv.w += a*ev.w;
      }
      *(float4*)(pctx + (seg*80+h4)*4) = accv;
    }
    __syncthreads();
    if (tid < 80){
      float4 p0 = *(float4*)(pctx + tid*4);
      float4 p1 = *(float4*)(pctx + (80+tid)*4);
      float4 p2v = *(float4*)(pctx + (160+tid)*4);
      float4 cvv;
      cvv.x = p0.x+p1.x+p2v.x; cvv.y = p0.y+p1.y+p2v.y;
      cvv.z = p0.z+p1.z+p2v.z; cvv.w = p0.w+p1.w+p2v.w;
      *(float4*)(ctxL + tid*4) = cvv;
    }
    __syncthreads();
    if (tid < 224){
      int g = tid >> 2, ks = tid & 3;
      const float* wr = A.W1 + (size_t)g*516;
      float acc = 0.f;
      #pragma unroll 4
      for (int q = ks; q < 516; q += 4){
        float hv = (q < 196) ? hl2[q] : ctxL[q-196];
        acc += hv*wr[q];
      }
      acc += __shfl_down(acc,2,4); acc += __shfl_down(acc,1,4);
      if (ks == 0) astore(&A.uAll[(size_t)s*1792 + b*56 + g], fast_tanh(acc + b1L[g]));
    } else {
      int l = tid - 224; float acc = 0.f;
      for (int q = l; q < 320; q += 32) acc += ctxL[q]*WcsL[q];
      #pragma unroll
      for (int o=16;o;o>>=1) acc += __shfl_down(acc,o,32);
      if (l==0) astore(&A.ctxWAll[s*32 + b], acc);
    }
    __syncthreads();                 // drains vmcnt
    if (tid == 0) set_slot(fP2P + s*32 + b);
  }
}

// ---------------- host launch ----------------
extern "C" void kernel_launch(void* const* d_in, const int* in_sizes, int n_in,
                              void* d_out, int out_size, void* d_ws, size_t ws_size,
                              hipStream_t stream){
  const int*   in_ids = (const int*)  d_in[0];
  const int*   tgt    = (const int*)  d_in[1];
  const float* emb    = (const float*)d_in[3];
  const float* Wi_f   = (const float*)d_in[4];
  const float* Wh_f   = (const float*)d_in[5];
  const float* bi_f   = (const float*)d_in[6];
  const float* bh_f   = (const float*)d_in[7];
  const float* Wi_b   = (const float*)d_in[8];
  const float* Wh_b   = (const float*)d_in[9];
  const float* bi_b   = (const float*)d_in[10];
  const float* bh_b   = (const float*)d_in[11];
  const float* Weh    = (const float*)d_in[12];
  const float* beh    = (const float*)d_in[13];
  const float* Wec    = (const float*)d_in[14];
  const float* bec    = (const float*)d_in[15];
  const float* Wi_d   = (const float*)d_in[16];
  const float* Wh_d   = (const float*)d_in[17];
  const float* bi_d   = (const float*)d_in[18];
  const float* bh_d   = (const float*)d_in[19];
  const float* Wea    = (const float*)d_in[20];
  const float* bea    = (const float*)d_in[21];
  const float* Wda    = (const float*)d_in[22];
  const float* Wca    = (const float*)d_in[23];
  const float* vat    = (const float*)d_in[24];
  const float* W1     = (const float*)d_in[25];
  const float* b1     = (const float*)d_in[26];
  const float* W2     = (const float*)d_in[27];
  const float* b2     = (const float*)d_in[28];
  const float* Wcs    = (const float*)d_in[29];
  const float* bcs    = (const float*)d_in[30];
  const float* Wds    = (const float*)d_in[31];
  const float* Wes    = (const float*)d_in[32];

  float* ws = (float*)d_ws;
  int* iBase = (int*)(ws + oFEnd);
  int* in_mapped = iBase;
  int* cur_ids   = iBase + 8192;
  unsigned* flags = (unsigned*)(iBase + 11392);

  prep_kernel<<<128, 256, 0, stream>>>(in_ids, tgt, in_mapped, cur_ids, flags);

  { RGTArgs a{in_mapped, emb, Wi_f, bi_f, bh_f, ws + oXf, 640};
    rowgemm_t<<<256, 256, 0, stream>>>(a); }
  { RGTArgs a{in_mapped, emb, Wi_b, bi_b, bh_b, ws + oXb, 640};
    rowgemm_t<<<256, 256, 0, stream>>>(a); }
  { RGTArgs a{cur_ids, emb, Wi_d, bi_d, bh_d, ws + oXd, 784};
    rowgemm_t<<<100, 256, 0, stream>>>(a); }

  es_kernel<<<3200, 64, 0, stream>>>(cur_ids, emb, Wes, ws + oEs);

  { EncArgs ea{ws + oXf, ws + oXb, Wh_f, Wh_b, ws + oHenc, ws + oCT, flags + fEnc};
    void* ka[] = {&ea};
    hipLaunchCooperativeKernel((void*)enc_scan, dim3(40), dim3(256), ka,
                               (unsigned)((5120 + 32*164)*4), stream); }

  mid_kernel<<<32, 256, 0, stream>>>(ws + oHenc, ws + oCT, Weh, beh, Wec, bec,
                                     ws + oH0, ws + oC0);

  encA_gemm<<<1024, 256, 0, stream>>>(ws + oHenc, Wea, bea, ws + oEncA);

  { DecArgs da{ws + oXd, ws + oHenc, ws + oEncA,
               ws + oH0, ws + oC0,
               Wh_d, Wda, Wca, vat,
               W1, b1, W2, b2, Wcs, bcs, Wds, ws + oEs,
               in_ids, tgt,
               ws + oHdAll, ws + oUAll, ws + oHWdsAll, ws + oCtxWAll, ws + oCopyAll,
               ws + oZidxAll, ws + oPartAll, ws + oClAll, ws + oNllWg, (float*)d_out,
               flags};
    void* ka[] = {&da};
    hipLaunchCooperativeKernel((void*)dec_scan, dim3(281), dim3(256), ka,
                               (unsigned)((6272 + 6400)*4), stream); }
}